// Round 4
// baseline (832.982 us; speedup 1.0000x reference)
//
#include <hip/hip_runtime.h>
#include <hip/hip_bf16.h>
#include <math.h>

#define TT 512
#define CC 768
#define HH 12
#define DD 64
#define KKEEP 64
#define TOPG 128
#define NTCE (TT * CC)

typedef __attribute__((ext_vector_type(8))) short bf16x8;
typedef __attribute__((ext_vector_type(8))) unsigned short ushort8v;
typedef __attribute__((ext_vector_type(4))) float f32x4;
typedef unsigned long long u64;

// ---------------- helpers ----------------
__device__ __forceinline__ float block_sum(float v, float* red) {
#pragma unroll
  for (int off = 32; off; off >>= 1) v += __shfl_xor(v, off);
  __syncthreads();
  if ((threadIdx.x & 63) == 0) red[threadIdx.x >> 6] = v;
  __syncthreads();
  return red[0] + red[1] + red[2] + red[3];
}

__device__ __forceinline__ unsigned short f32_to_bf16_rne(float f) {
  unsigned u = __float_as_uint(f);
  unsigned r = (u + 0x7FFFu + ((u >> 16) & 1u)) >> 16;
  return (unsigned short)r;
}
__device__ __forceinline__ float bf16_to_f32(unsigned short h) {
  return __uint_as_float(((unsigned)h) << 16);
}
__device__ __forceinline__ void split2(float x, unsigned short& h, unsigned short& l) {
  h = f32_to_bf16_rne(x);
  l = f32_to_bf16_rne(x - bf16_to_f32(h));
}
__device__ __forceinline__ int swz(int row, int k) {
  return row * 64 + ((((k >> 3) ^ (row & 7))) << 3) + (k & 7);
}

// ---------------- weight split+transpose (all 10 weights, one dispatch) ----------------
struct WSplitArgs {
  const float* src[10];
  unsigned short* hi[10];
  unsigned short* lo[10];
  int K[10], N[10], tstart[10];
};

__global__ __launch_bounds__(256) void wsplitT_kernel(WSplitArgs a) {
  __shared__ float tile_[64][65];
  int t = blockIdx.x;
  int wsel = 0;
#pragma unroll
  for (int i = 1; i < 10; i++)
    if (t >= a.tstart[i]) wsel = i;
  int local = t - a.tstart[wsel];
  int K = a.K[wsel], N = a.N[wsel];
  int ntn = N >> 6;
  int bn = local % ntn, bk = local / ntn;
  int tid = threadIdx.x, r = tid >> 2, cq = tid & 3;
  const float* src = a.src[wsel] + (size_t)(bk * 64 + r) * N + bn * 64 + cq * 16;
#pragma unroll
  for (int f = 0; f < 4; f++) {
    float4 v = *(const float4*)(src + f * 4);
    tile_[r][cq * 16 + f * 4 + 0] = v.x;
    tile_[r][cq * 16 + f * 4 + 1] = v.y;
    tile_[r][cq * 16 + f * 4 + 2] = v.z;
    tile_[r][cq * 16 + f * 4 + 3] = v.w;
  }
  __syncthreads();
  size_t dst = (size_t)(bn * 64 + r) * K + bk * 64 + cq * 16;
  unsigned short hv[16], lv[16];
#pragma unroll
  for (int i = 0; i < 16; i++) split2(tile_[cq * 16 + i][r], hv[i], lv[i]);
  *(ushort8v*)&a.hi[wsel][dst] = *(const ushort8v*)&hv[0];
  *(ushort8v*)&a.hi[wsel][dst + 8] = *(const ushort8v*)&hv[8];
  *(ushort8v*)&a.lo[wsel][dst] = *(const ushort8v*)&lv[0];
  *(ushort8v*)&a.lo[wsel][dst + 8] = *(const ushort8v*)&lv[8];
}

// ---------------- layernorm (f32 out optional, split-bf16 planes out) ----------------
__global__ void ln_bf_kernel(const float* __restrict__ x, const float* __restrict__ w,
                             const float* __restrict__ b, float* __restrict__ outf,
                             unsigned short* __restrict__ ohi, unsigned short* __restrict__ olo) {
  int t = blockIdx.x, tid = threadIdx.x;
  __shared__ float red[4];
  float ls = 0.f;
  for (int c = tid; c < CC; c += 256) ls += x[t * CC + c];
  float mean = block_sum(ls, red) * (1.f / CC);
  float lv = 0.f;
  for (int c = tid; c < CC; c += 256) { float d = x[t * CC + c] - mean; lv += d * d; }
  float var = block_sum(lv, red) * (1.f / CC);
  float rs = rsqrtf(var + 1e-5f);
  for (int c = tid; c < CC; c += 256) {
    float val = (x[t * CC + c] - mean) * rs * w[c] + b[c];
    if (outf) outf[t * CC + c] = val;
    unsigned short hb, lb;
    split2(val, hb, lb);
    ohi[t * CC + c] = hb;
    olo[t * CC + c] = lb;
  }
}

// ---------------- split-bf16 MFMA GEMM from preconverted planes ----------------
// A planes [M][K]; B planes transposed [N][K]; out f32 (opt, seg) and/or planes (opt)
__global__ __launch_bounds__(256) void gemm_bf(
    const unsigned short* __restrict__ Ah, const unsigned short* __restrict__ Al,
    const unsigned short* __restrict__ Bh, const unsigned short* __restrict__ Bl,
    const float* __restrict__ bias, float* __restrict__ Cf,
    unsigned short* __restrict__ Chi, unsigned short* __restrict__ Clo,
    int M, int N, int K, int act, int seg) {
  __shared__ unsigned short AsH[64 * 64], AsL[64 * 64], BsH[64 * 64], BsL[64 * 64];
  int tid = threadIdx.x, lane = tid & 63, wave = tid >> 6;
  int wr = wave >> 1, wc = wave & 1, lr = lane & 15;
  int ksub = (lane >> 4) * 8;
  int n0 = blockIdx.x * 64, m0 = blockIdx.y * 64;
  int lrow = tid >> 2, lq = tid & 3;

  f32x4 acc[2][2];
#pragma unroll
  for (int i = 0; i < 2; i++)
#pragma unroll
    for (int j = 0; j < 2; j++) acc[i][j] = (f32x4){0.f, 0.f, 0.f, 0.f};

  for (int k0 = 0; k0 < K; k0 += 64) {
    size_t aoff = (size_t)(m0 + lrow) * K + k0 + lq * 16;
    size_t boff = (size_t)(n0 + lrow) * K + k0 + lq * 16;
    int d0 = lrow * 64 + (((lq * 2) ^ (lrow & 7)) << 3);
    int d1 = lrow * 64 + (((lq * 2 + 1) ^ (lrow & 7)) << 3);
    *(ushort8v*)&AsH[d0] = *(const ushort8v*)&Ah[aoff];
    *(ushort8v*)&AsH[d1] = *(const ushort8v*)&Ah[aoff + 8];
    *(ushort8v*)&AsL[d0] = *(const ushort8v*)&Al[aoff];
    *(ushort8v*)&AsL[d1] = *(const ushort8v*)&Al[aoff + 8];
    *(ushort8v*)&BsH[d0] = *(const ushort8v*)&Bh[boff];
    *(ushort8v*)&BsH[d1] = *(const ushort8v*)&Bh[boff + 8];
    *(ushort8v*)&BsL[d0] = *(const ushort8v*)&Bl[boff];
    *(ushort8v*)&BsL[d1] = *(const ushort8v*)&Bl[boff + 8];
    __syncthreads();
#pragma unroll
    for (int kb = 0; kb < 2; kb++) {
      int kloc = kb * 32 + ksub;
      bf16x8 ah[2], al[2], bh[2], bl[2];
#pragma unroll
      for (int i = 0; i < 2; i++) {
        int m = wr * 32 + i * 16 + lr;
        int off = swz(m, kloc);
        ah[i] = *(const bf16x8*)&AsH[off];
        al[i] = *(const bf16x8*)&AsL[off];
      }
#pragma unroll
      for (int j = 0; j < 2; j++) {
        int n = wc * 32 + j * 16 + lr;
        int off = swz(n, kloc);
        bh[j] = *(const bf16x8*)&BsH[off];
        bl[j] = *(const bf16x8*)&BsL[off];
      }
#pragma unroll
      for (int i = 0; i < 2; i++)
#pragma unroll
        for (int j = 0; j < 2; j++) {
          acc[i][j] = __builtin_amdgcn_mfma_f32_16x16x32_bf16(ah[i], bh[j], acc[i][j], 0, 0, 0);
          acc[i][j] = __builtin_amdgcn_mfma_f32_16x16x32_bf16(ah[i], bl[j], acc[i][j], 0, 0, 0);
          acc[i][j] = __builtin_amdgcn_mfma_f32_16x16x32_bf16(al[i], bh[j], acc[i][j], 0, 0, 0);
        }
    }
    __syncthreads();
  }
#pragma unroll
  for (int i = 0; i < 2; i++)
#pragma unroll
    for (int j = 0; j < 2; j++) {
      int col = n0 + wc * 32 + j * 16 + lr;
      float bv = bias ? bias[col] : 0.f;
#pragma unroll
      for (int q = 0; q < 4; q++) {
        int row = m0 + wr * 32 + i * 16 + (lane >> 4) * 4 + q;
        float v = acc[i][j][q] + bv;
        if (act == 1) v = 0.5f * v * (1.f + erff(v * 0.70710678118654752f));
        if (Cf) {
          size_t off = seg ? (size_t)(col / CC) * NTCE + (size_t)row * CC + (col % CC)
                           : (size_t)row * N + col;
          Cf[off] = v;
        }
        if (Chi) {
          size_t o2 = (size_t)row * N + col;
          unsigned short hb, lb;
          split2(v, hb, lb);
          Chi[o2] = hb;
          Clo[o2] = lb;
        }
      }
    }
}

// ---------------- causal SDPA (planes out) ----------------
__global__ void sdpa_kernel(const float* __restrict__ qkv,
                            unsigned short* __restrict__ yhi, unsigned short* __restrict__ ylo) {
  int h = blockIdx.x, t = blockIdx.y, tid = threadIdx.x;
  __shared__ float qv[DD];
  __shared__ float sc[TT];
  __shared__ float red[4];
  __shared__ float acc2[4][DD];
  if (tid < DD) qv[tid] = qkv[t * 3 * CC + h * DD + tid];
  __syncthreads();
  float lmax = -INFINITY;
  for (int s = tid; s <= t; s += 256) {
    const float* Kp = qkv + s * 3 * CC + CC + h * DD;
    float d = 0.f;
#pragma unroll
    for (int i = 0; i < DD; i++) d += qv[i] * Kp[i];
    d *= 0.125f;
    sc[s] = d;
    lmax = fmaxf(lmax, d);
  }
  {
#pragma unroll
    for (int off = 32; off; off >>= 1) lmax = fmaxf(lmax, __shfl_xor(lmax, off));
    __syncthreads();
    if ((tid & 63) == 0) red[tid >> 6] = lmax;
    __syncthreads();
    lmax = fmaxf(fmaxf(red[0], red[1]), fmaxf(red[2], red[3]));
  }
  float lsum = 0.f;
  for (int s = tid; s <= t; s += 256) { float e = expf(sc[s] - lmax); sc[s] = e; lsum += e; }
  float sum = block_sum(lsum, red);
  __syncthreads();
  int d = tid & 63, c = tid >> 6;
  float part = 0.f;
  for (int s = c; s <= t; s += 4) part += sc[s] * qkv[s * 3 * CC + 2 * CC + h * DD + d];
  acc2[c][d] = part;
  __syncthreads();
  if (tid < DD) {
    float tot = (acc2[0][tid] + acc2[1][tid] + acc2[2][tid] + acc2[3][tid]) / sum;
    unsigned short hb, lb;
    split2(tot, hb, lb);
    yhi[t * CC + h * DD + tid] = hb;
    ylo[t * CC + h * DD + tid] = lb;
  }
}

// ---------------- register bitonic sort of 512 u64 keys across one wave ----------------
__device__ __forceinline__ void sort512(u64* key, int lane) {
#pragma unroll
  for (int k = 2; k <= 512; k <<= 1) {
#pragma unroll
    for (int j = k >> 1; j > 0; j >>= 1) {
      if (j < 64) {
        bool lower = (lane & j) == 0;
#pragma unroll
        for (int e = 0; e < 8; e++) {
          bool desc = ((((e << 6) | lane) & k) == 0);
          u64 part = __shfl_xor(key[e], j);
          bool wantmax = (desc == lower);
          key[e] = (wantmax ? (part > key[e]) : (part < key[e])) ? part : key[e];
        }
      } else {
        int m = j >> 6;
#pragma unroll
        for (int e = 0; e < 8; e++) {
          if ((e & m) == 0) {
            int e2 = e | m;
            bool desc = ((((e << 6) | lane) & k) == 0);
            u64 a = key[e], b = key[e2];
            u64 mx = a > b ? a : b;
            u64 mn = a > b ? b : a;
            key[e] = desc ? mx : mn;
            key[e2] = desc ? mn : mx;
          }
        }
      }
    }
  }
}

// ---------------- HOA top-64: one wave per (branch,h,t) row ----------------
__global__ __launch_bounds__(256) void topk_wave_kernel(
    const float* __restrict__ qh, const float* __restrict__ K1,
    const float* __restrict__ K2, int* __restrict__ idx1, int* __restrict__ idx2) {
  __shared__ float qsh[4][64];
  int tid = threadIdx.x, lane = tid & 63, w = tid >> 6;
  int row = blockIdx.x * 4 + w;
  int br = row >= (HH * TT) ? 1 : 0;
  int rem = row - br * (HH * TT);
  int h = rem >> 9, t = rem & (TT - 1);
  qsh[w][lane] = qh[(size_t)t * CC + h * DD + lane];
  const float* Kb = (br ? K2 : K1) + h * DD;
  float acc[8] = {0.f, 0.f, 0.f, 0.f, 0.f, 0.f, 0.f, 0.f};
#pragma unroll
  for (int c = 0; c < 4; c++) {
    float4 q4[4];
#pragma unroll
    for (int u = 0; u < 4; u++) q4[u] = *(const float4*)&qsh[w][c * 16 + u * 4];
#pragma unroll
    for (int e = 0; e < 8; e++) {
      const float* kp = Kb + (size_t)(e * 64 + lane) * CC + c * 16;
#pragma unroll
      for (int u = 0; u < 4; u++) {
        float4 k4 = *(const float4*)(kp + u * 4);
        acc[e] += q4[u].x * k4.x;
        acc[e] += q4[u].y * k4.y;
        acc[e] += q4[u].z * k4.z;
        acc[e] += q4[u].w * k4.w;
      }
    }
  }
  u64 key[8];
#pragma unroll
  for (int e = 0; e < 8; e++) {
    int s = e * 64 + lane;
    unsigned sv = 0u;
    if (s <= t) {
      unsigned uu = __float_as_uint(acc[e]);
      sv = (uu & 0x80000000u) ? ~uu : (uu | 0x80000000u);
    }
    key[e] = ((u64)sv << 32) | (unsigned)(~s);
  }
  sort512(key, lane);
  unsigned myidx = ~(unsigned)key[0];
  unsigned outv = __shfl(myidx, min(lane, t));
  int* idxout = (br ? idx2 : idx1) + ((size_t)h * TT + t) * KKEEP;
  idxout[lane] = (int)outv;
}

// ---------------- HOA core: MFMA (per (h,t) block, 4 waves), planes out ----------------
__global__ __launch_bounds__(256) void hoa_core_kernel(
    const float* __restrict__ qh,
    const float* __restrict__ K1, const float* __restrict__ K2,
    const float* __restrict__ V1, const float* __restrict__ V2,
    const int* __restrict__ idx1, const int* __restrict__ idx2,
    unsigned short* __restrict__ hcohi, unsigned short* __restrict__ hcolo) {
  int h = blockIdx.x, t = blockIdx.y, tid = threadIdx.x;
  int lane = tid & 63, w = tid >> 6;
  int lr = lane & 15;
  int ksub = (lane >> 4) * 8;
  const int hDD = h * DD;

  __shared__ unsigned short bufA[64 * 64];
  __shared__ unsigned short bufB[64 * 64];
  __shared__ float v1s[64 * 65];
  __shared__ float red[4 * 64];

  const int* i1 = idx1 + (h * TT + t) * KKEEP;
  const int* i2 = idx2 + (h * TT + t) * KKEEP;

  float qreg = qh[t * CC + hDD + lane];

#pragma unroll
  for (int r = 0; r < 16; r++) {
    int j = w * 16 + r;
    int r1 = i1[j], r2 = i2[j];
    float k1v = K1[(size_t)r1 * CC + hDD + lane];
    float k2v = K2[(size_t)r2 * CC + hDD + lane];
    float v1v = V1[(size_t)r1 * CC + hDD + lane];
    int off = swz(j, lane);
    bufA[off] = f32_to_bf16_rne(k1v * qreg);
    bufB[off] = f32_to_bf16_rne(k2v);
    v1s[j * 65 + lane] = v1v;
  }
  __syncthreads();

  f32x4 acc[4];
#pragma unroll
  for (int nt = 0; nt < 4; nt++) acc[nt] = (f32x4){0.f, 0.f, 0.f, 0.f};
  {
    bf16x8 af[2];
#pragma unroll
    for (int kb = 0; kb < 2; kb++)
      af[kb] = *(const bf16x8*)&bufA[swz(w * 16 + lr, kb * 32 + ksub)];
#pragma unroll
    for (int nt = 0; nt < 4; nt++)
#pragma unroll
      for (int kb = 0; kb < 2; kb++) {
        bf16x8 bf = *(const bf16x8*)&bufB[swz(nt * 16 + lr, kb * 32 + ksub)];
        acc[nt] = __builtin_amdgcn_mfma_f32_16x16x32_bf16(af[kb], bf, acc[nt], 0, 0, 0);
      }
  }
#pragma unroll
  for (int q = 0; q < 4; q++) {
    float m = -INFINITY;
#pragma unroll
    for (int nt = 0; nt < 4; nt++) {
      acc[nt][q] *= 0.125f;
      m = fmaxf(m, acc[nt][q]);
    }
#pragma unroll
    for (int off = 1; off < 16; off <<= 1) m = fmaxf(m, __shfl_xor(m, off));
    float s = 0.f;
#pragma unroll
    for (int nt = 0; nt < 4; nt++) {
      float e = expf(acc[nt][q] - m);
      acc[nt][q] = e;
      s += e;
    }
#pragma unroll
    for (int off = 1; off < 16; off <<= 1) s += __shfl_xor(s, off);
    float inv = 1.f / s;
#pragma unroll
    for (int nt = 0; nt < 4; nt++) acc[nt][q] *= inv;
  }
  __syncthreads();

#pragma unroll
  for (int nt = 0; nt < 4; nt++)
#pragma unroll
    for (int q = 0; q < 4; q++) {
      int row = w * 16 + (lane >> 4) * 4 + q;
      int col = nt * 16 + lr;
      bufA[swz(row, col)] = f32_to_bf16_rne(acc[nt][q]);
    }
#pragma unroll
  for (int r = 0; r < 16; r++) {
    int k = w * 16 + r;
    float v2v = V2[(size_t)i2[k] * CC + hDD + lane];
    bufB[swz(lane, k)] = f32_to_bf16_rne(v2v);
  }
  __syncthreads();

  f32x4 acc2[4];
#pragma unroll
  for (int nt = 0; nt < 4; nt++) acc2[nt] = (f32x4){0.f, 0.f, 0.f, 0.f};
  {
    bf16x8 af[2];
#pragma unroll
    for (int kb = 0; kb < 2; kb++)
      af[kb] = *(const bf16x8*)&bufA[swz(w * 16 + lr, kb * 32 + ksub)];
#pragma unroll
    for (int nt = 0; nt < 4; nt++)
#pragma unroll
      for (int kb = 0; kb < 2; kb++) {
        bf16x8 bf = *(const bf16x8*)&bufB[swz(nt * 16 + lr, kb * 32 + ksub)];
        acc2[nt] = __builtin_amdgcn_mfma_f32_16x16x32_bf16(af[kb], bf, acc2[nt], 0, 0, 0);
      }
  }
#pragma unroll
  for (int nt = 0; nt < 4; nt++) {
    float p = 0.f;
#pragma unroll
    for (int q = 0; q < 4; q++) {
      int row = w * 16 + (lane >> 4) * 4 + q;
      int col = lr + 16 * nt;
      p += acc2[nt][q] * v1s[row * 65 + col];
    }
    p += __shfl_xor(p, 16);
    p += __shfl_xor(p, 32);
    if (lane < 16) red[w * 64 + 16 * nt + lr] = p;
  }
  __syncthreads();
  if (tid < 64) {
    float o = red[tid] + red[64 + tid] + red[128 + tid] + red[192 + tid];
    unsigned short hb, lb;
    split2(o, hb, lb);
    hcohi[t * CC + hDD + tid] = hb;
    hcolo[t * CC + hDD + tid] = lb;
  }
}

// ---------------- gate ----------------
__global__ void gate_scores_kernel(const float* __restrict__ hoin,
                                   const float* __restrict__ gw, const float* __restrict__ gb,
                                   float* __restrict__ scores) {
  int t = blockIdx.x, tid = threadIdx.x;
  __shared__ float red[4];
  float part = 0.f;
  for (int c = tid; c < CC; c += 256) part += hoin[t * CC + c] * gw[c];
  float s = block_sum(part, red);
  if (tid == 0) scores[t] = s + gb[0];
}

__global__ void gate_mask_kernel(const float* __restrict__ scores, float* __restrict__ mask) {
  int lane = threadIdx.x;  // 64 threads, one wave
  u64 key[8];
#pragma unroll
  for (int e = 0; e < 8; e++) {
    int s = e * 64 + lane;
    unsigned uu = __float_as_uint(scores[s]);
    unsigned sv = (uu & 0x80000000u) ? ~uu : (uu | 0x80000000u);
    key[e] = ((u64)sv << 32) | (unsigned)(~s);
    mask[s] = 0.f;
  }
  __asm__ volatile("s_waitcnt vmcnt(0)" ::: "memory");
  sort512(key, lane);
#pragma unroll
  for (int e = 0; e < 2; e++) mask[(int)(~(unsigned)key[e])] = 1.f;
}

// ---------------- elementwise ----------------
__global__ void add_kernel(const float* __restrict__ a, const float* __restrict__ b,
                           float* __restrict__ o, int n) {
  int i = blockIdx.x * 256 + threadIdx.x;
  if (i < n) o[i] = a[i] + b[i];
}

__global__ void masked_add_kernel(const float* __restrict__ a, const float* __restrict__ b,
                                  const float* __restrict__ mask, float* __restrict__ o, int n) {
  int i = blockIdx.x * 256 + threadIdx.x;
  if (i < n) o[i] = a[i] + b[i] * mask[i / CC];
}

// ---------------- launcher ----------------
extern "C" void kernel_launch(void* const* d_in, const int* in_sizes, int n_in,
                              void* d_out, int out_size, void* d_ws, size_t ws_size,
                              hipStream_t stream) {
  const float* x      = (const float*)d_in[0];
  const float* ln1_w  = (const float*)d_in[1];
  const float* ln1_b  = (const float*)d_in[2];
  const float* qkv_w  = (const float*)d_in[3];
  const float* qkv_b  = (const float*)d_in[4];
  const float* atto_w = (const float*)d_in[5];
  const float* atto_b = (const float*)d_in[6];
  const float* lnh_w  = (const float*)d_in[7];
  const float* lnh_b  = (const float*)d_in[8];
  const float* hq_w   = (const float*)d_in[9];
  const float* hk1_w  = (const float*)d_in[10];
  const float* hk2_w  = (const float*)d_in[11];
  const float* hv1_w  = (const float*)d_in[12];
  const float* hv2_w  = (const float*)d_in[13];
  const float* ho_w   = (const float*)d_in[14];
  const float* gate_w = (const float*)d_in[15];
  const float* gate_b = (const float*)d_in[16];
  const float* ln2_w  = (const float*)d_in[17];
  const float* ln2_b  = (const float*)d_in[18];
  const float* fc_w   = (const float*)d_in[19];
  const float* fc_b   = (const float*)d_in[20];
  const float* pr_w   = (const float*)d_in[21];
  const float* pr_b   = (const float*)d_in[22];
  float* out = (float*)d_out;

  // workspace carve-up
  char* cur = (char*)d_ws;
  auto alloc = [&](size_t bytes) {
    char* p = cur;
    cur += (bytes + 255) & ~(size_t)255;
    return p;
  };
  float* qkv  = (float*)alloc((size_t)3 * NTCE * 4);
  float* x1   = (float*)alloc((size_t)NTCE * 4);
  float* hoin = (float*)alloc((size_t)NTCE * 4);
  float* qh   = (float*)alloc((size_t)5 * NTCE * 4);  // qh,K1,K2,V1,V2 contiguous
  float* K1   = qh + NTCE;
  float* K2   = K1 + NTCE;
  float* V1   = K2 + NTCE;
  float* V2   = V1 + NTCE;
  float* hout = (float*)alloc((size_t)NTCE * 4);
  float* x2   = (float*)alloc((size_t)NTCE * 4);
  float* tmp  = (float*)alloc((size_t)NTCE * 4);
  float* scores = (float*)alloc(TT * 4);
  float* maskb  = (float*)alloc(TT * 4);
  int* idx1 = (int*)alloc((size_t)HH * TT * KKEEP * 4);
  int* idx2 = (int*)alloc((size_t)HH * TT * KKEEP * 4);
  // activation planes
  unsigned short* hHi    = (unsigned short*)alloc((size_t)NTCE * 2);
  unsigned short* hLo    = (unsigned short*)alloc((size_t)NTCE * 2);
  unsigned short* yHi    = (unsigned short*)alloc((size_t)NTCE * 2);
  unsigned short* yLo    = (unsigned short*)alloc((size_t)NTCE * 2);
  unsigned short* hoinHi = (unsigned short*)alloc((size_t)NTCE * 2);
  unsigned short* hoinLo = (unsigned short*)alloc((size_t)NTCE * 2);
  unsigned short* h2Hi   = (unsigned short*)alloc((size_t)NTCE * 2);
  unsigned short* h2Lo   = (unsigned short*)alloc((size_t)NTCE * 2);
  unsigned short* hcoHi  = (unsigned short*)alloc((size_t)NTCE * 2);
  unsigned short* hcoLo  = (unsigned short*)alloc((size_t)NTCE * 2);
  unsigned short* fcbHi  = (unsigned short*)alloc((size_t)4 * NTCE * 2);
  unsigned short* fcbLo  = (unsigned short*)alloc((size_t)4 * NTCE * 2);
  // weight planes (transposed [N][K])
  const size_t WSQ = (size_t)CC * CC;
  unsigned short* qkvT_h = (unsigned short*)alloc((size_t)CC * 3 * CC * 2);
  unsigned short* qkvT_l = (unsigned short*)alloc((size_t)CC * 3 * CC * 2);
  unsigned short* attoT_h = (unsigned short*)alloc(WSQ * 2);
  unsigned short* attoT_l = (unsigned short*)alloc(WSQ * 2);
  unsigned short* hoaT_h = (unsigned short*)alloc(5 * WSQ * 2);
  unsigned short* hoaT_l = (unsigned short*)alloc(5 * WSQ * 2);
  unsigned short* hoT_h = (unsigned short*)alloc(WSQ * 2);
  unsigned short* hoT_l = (unsigned short*)alloc(WSQ * 2);
  unsigned short* fcT_h = (unsigned short*)alloc((size_t)CC * 4 * CC * 2);
  unsigned short* fcT_l = (unsigned short*)alloc((size_t)CC * 4 * CC * 2);
  unsigned short* prT_h = (unsigned short*)alloc((size_t)CC * 4 * CC * 2);
  unsigned short* prT_l = (unsigned short*)alloc((size_t)CC * 4 * CC * 2);

  // weight split jobs
  WSplitArgs wa;
  int tcur = 0;
  auto addw = [&](int i, const float* s, unsigned short* hi, unsigned short* lo, int K, int N) {
    wa.src[i] = s; wa.hi[i] = hi; wa.lo[i] = lo;
    wa.K[i] = K; wa.N[i] = N; wa.tstart[i] = tcur;
    tcur += (N / 64) * (K / 64);
  };
  addw(0, qkv_w, qkvT_h, qkvT_l, CC, 3 * CC);
  addw(1, atto_w, attoT_h, attoT_l, CC, CC);
  addw(2, hq_w,  hoaT_h + 0 * WSQ, hoaT_l + 0 * WSQ, CC, CC);
  addw(3, hk1_w, hoaT_h + 1 * WSQ, hoaT_l + 1 * WSQ, CC, CC);
  addw(4, hk2_w, hoaT_h + 2 * WSQ, hoaT_l + 2 * WSQ, CC, CC);
  addw(5, hv1_w, hoaT_h + 3 * WSQ, hoaT_l + 3 * WSQ, CC, CC);
  addw(6, hv2_w, hoaT_h + 4 * WSQ, hoaT_l + 4 * WSQ, CC, CC);
  addw(7, ho_w, hoT_h, hoT_l, CC, CC);
  addw(8, fc_w, fcT_h, fcT_l, CC, 4 * CC);
  addw(9, pr_w, prT_h, prT_l, 4 * CC, CC);

  dim3 blk(256);
  int nElem = NTCE;
  int nBlocks = (nElem + 255) / 256;

  hipLaunchKernelGGL(wsplitT_kernel, dim3(tcur), blk, 0, stream, wa);
  // LN1 -> h planes
  hipLaunchKernelGGL(ln_bf_kernel, dim3(TT), blk, 0, stream, x, ln1_w, ln1_b,
                     (float*)nullptr, hHi, hLo);
  // QKV
  hipLaunchKernelGGL(gemm_bf, dim3(36, 8), blk, 0, stream, hHi, hLo, qkvT_h, qkvT_l,
                     qkv_b, qkv, (unsigned short*)nullptr, (unsigned short*)nullptr,
                     TT, 3 * CC, CC, 0, 0);
  // SDPA -> y planes
  hipLaunchKernelGGL(sdpa_kernel, dim3(HH, TT), blk, 0, stream, qkv, yHi, yLo);
  // atto -> tmp
  hipLaunchKernelGGL(gemm_bf, dim3(12, 8), blk, 0, stream, yHi, yLo, attoT_h, attoT_l,
                     atto_b, tmp, (unsigned short*)nullptr, (unsigned short*)nullptr,
                     TT, CC, CC, 0, 0);
  hipLaunchKernelGGL(add_kernel, dim3(nBlocks), blk, 0, stream, x, tmp, x1, nElem);
  // LNh -> hoin f32 + planes
  hipLaunchKernelGGL(ln_bf_kernel, dim3(TT), blk, 0, stream, x1, lnh_w, lnh_b,
                     hoin, hoinHi, hoinLo);
  // 5 HOA projections merged (N=3840, segmented out to qh..V2)
  hipLaunchKernelGGL(gemm_bf, dim3(60, 8), blk, 0, stream, hoinHi, hoinLo, hoaT_h, hoaT_l,
                     (const float*)nullptr, qh, (unsigned short*)nullptr, (unsigned short*)nullptr,
                     TT, 5 * CC, CC, 0, 1);
  // top-64 (both branches, wave-per-row)
  hipLaunchKernelGGL(topk_wave_kernel, dim3(2 * HH * TT / 4), blk, 0, stream,
                     qh, K1, K2, idx1, idx2);
  // HOA core -> hco planes
  hipLaunchKernelGGL(hoa_core_kernel, dim3(HH, TT), blk, 0, stream,
                     qh, K1, K2, V1, V2, idx1, idx2, hcoHi, hcoLo);
  // ho -> hout
  hipLaunchKernelGGL(gemm_bf, dim3(12, 8), blk, 0, stream, hcoHi, hcoLo, hoT_h, hoT_l,
                     (const float*)nullptr, hout, (unsigned short*)nullptr, (unsigned short*)nullptr,
                     TT, CC, CC, 0, 0);
  // gate
  hipLaunchKernelGGL(gate_scores_kernel, dim3(TT), blk, 0, stream, hoin, gate_w, gate_b, scores);
  hipLaunchKernelGGL(gate_mask_kernel, dim3(1), dim3(64), 0, stream, scores, maskb);
  hipLaunchKernelGGL(masked_add_kernel, dim3(nBlocks), blk, 0, stream, x1, hout, maskb, x2, nElem);
  // LN2 -> h2 planes
  hipLaunchKernelGGL(ln_bf_kernel, dim3(TT), blk, 0, stream, x2, ln2_w, ln2_b,
                     (float*)nullptr, h2Hi, h2Lo);
  // fc (+gelu) -> fcb planes
  hipLaunchKernelGGL(gemm_bf, dim3(48, 8), blk, 0, stream, h2Hi, h2Lo, fcT_h, fcT_l,
                     fc_b, (float*)nullptr, fcbHi, fcbLo, TT, 4 * CC, CC, 1, 0);
  // pr -> tmp
  hipLaunchKernelGGL(gemm_bf, dim3(12, 8), blk, 0, stream, fcbHi, fcbLo, prT_h, prT_l,
                     pr_b, tmp, (unsigned short*)nullptr, (unsigned short*)nullptr,
                     TT, CC, 4 * CC, 0, 0);
  hipLaunchKernelGGL(add_kernel, dim3(nBlocks), blk, 0, stream, x2, tmp, out, nElem);
}

// Round 5
// 408.489 us; speedup vs baseline: 2.0392x; 2.0392x over previous
//
#include <hip/hip_runtime.h>
#include <hip/hip_bf16.h>
#include <math.h>

#define TT 512
#define CC 768
#define HH 12
#define DD 64
#define KKEEP 64
#define TOPG 128
#define NTCE (TT * CC)

typedef __attribute__((ext_vector_type(8))) short bf16x8;
typedef __attribute__((ext_vector_type(8))) unsigned short ushort8v;
typedef __attribute__((ext_vector_type(4))) float f32x4;
typedef unsigned long long u64;

// ---------------- helpers ----------------
__device__ __forceinline__ float block_sum(float v, float* red) {
#pragma unroll
  for (int off = 32; off; off >>= 1) v += __shfl_xor(v, off);
  __syncthreads();
  if ((threadIdx.x & 63) == 0) red[threadIdx.x >> 6] = v;
  __syncthreads();
  return red[0] + red[1] + red[2] + red[3];
}

__device__ __forceinline__ unsigned short f32_to_bf16_rne(float f) {
  unsigned u = __float_as_uint(f);
  unsigned r = (u + 0x7FFFu + ((u >> 16) & 1u)) >> 16;
  return (unsigned short)r;
}
__device__ __forceinline__ float bf16_to_f32(unsigned short h) {
  return __uint_as_float(((unsigned)h) << 16);
}
__device__ __forceinline__ void split2(float x, unsigned short& h, unsigned short& l) {
  h = f32_to_bf16_rne(x);
  l = f32_to_bf16_rne(x - bf16_to_f32(h));
}
__device__ __forceinline__ int swz(int row, int k) {
  return row * 64 + ((((k >> 3) ^ (row & 7))) << 3) + (k & 7);
}

// ---------------- weight split+transpose (all 10 weights, one dispatch) ----------------
struct WSplitArgs {
  const float* src[10];
  unsigned short* hi[10];
  unsigned short* lo[10];
  int K[10], N[10], tstart[10];
};

__global__ __launch_bounds__(256) void wsplitT_kernel(WSplitArgs a) {
  __shared__ float tile_[64][65];
  int t = blockIdx.x;
  int wsel = 0;
#pragma unroll
  for (int i = 1; i < 10; i++)
    if (t >= a.tstart[i]) wsel = i;
  int local = t - a.tstart[wsel];
  int K = a.K[wsel], N = a.N[wsel];
  int ntn = N >> 6;
  int bn = local % ntn, bk = local / ntn;
  int tid = threadIdx.x, r = tid >> 2, cq = tid & 3;
  const float* src = a.src[wsel] + (size_t)(bk * 64 + r) * N + bn * 64 + cq * 16;
#pragma unroll
  for (int f = 0; f < 4; f++) {
    float4 v = *(const float4*)(src + f * 4);
    tile_[r][cq * 16 + f * 4 + 0] = v.x;
    tile_[r][cq * 16 + f * 4 + 1] = v.y;
    tile_[r][cq * 16 + f * 4 + 2] = v.z;
    tile_[r][cq * 16 + f * 4 + 3] = v.w;
  }
  __syncthreads();
  size_t dst = (size_t)(bn * 64 + r) * K + bk * 64 + cq * 16;
  unsigned short hv[16], lv[16];
#pragma unroll
  for (int i = 0; i < 16; i++) split2(tile_[cq * 16 + i][r], hv[i], lv[i]);
  *(ushort8v*)&a.hi[wsel][dst] = *(const ushort8v*)&hv[0];
  *(ushort8v*)&a.hi[wsel][dst + 8] = *(const ushort8v*)&hv[8];
  *(ushort8v*)&a.lo[wsel][dst] = *(const ushort8v*)&lv[0];
  *(ushort8v*)&a.lo[wsel][dst + 8] = *(const ushort8v*)&lv[8];
}

// ---------------- layernorm (f32 out optional, split-bf16 planes out) ----------------
__global__ void ln_bf_kernel(const float* __restrict__ x, const float* __restrict__ w,
                             const float* __restrict__ b, float* __restrict__ outf,
                             unsigned short* __restrict__ ohi, unsigned short* __restrict__ olo) {
  int t = blockIdx.x, tid = threadIdx.x;
  __shared__ float red[4];
  float ls = 0.f;
  for (int c = tid; c < CC; c += 256) ls += x[t * CC + c];
  float mean = block_sum(ls, red) * (1.f / CC);
  float lv = 0.f;
  for (int c = tid; c < CC; c += 256) { float d = x[t * CC + c] - mean; lv += d * d; }
  float var = block_sum(lv, red) * (1.f / CC);
  float rs = rsqrtf(var + 1e-5f);
  for (int c = tid; c < CC; c += 256) {
    float val = (x[t * CC + c] - mean) * rs * w[c] + b[c];
    if (outf) outf[t * CC + c] = val;
    unsigned short hb, lb;
    split2(val, hb, lb);
    ohi[t * CC + c] = hb;
    olo[t * CC + c] = lb;
  }
}

// ---------------- split-bf16 MFMA GEMM from preconverted planes ----------------
__global__ __launch_bounds__(256) void gemm_bf(
    const unsigned short* __restrict__ Ah, const unsigned short* __restrict__ Al,
    const unsigned short* __restrict__ Bh, const unsigned short* __restrict__ Bl,
    const float* __restrict__ bias, float* __restrict__ Cf,
    unsigned short* __restrict__ Chi, unsigned short* __restrict__ Clo,
    int M, int N, int K, int act, int seg) {
  __shared__ unsigned short AsH[64 * 64], AsL[64 * 64], BsH[64 * 64], BsL[64 * 64];
  int tid = threadIdx.x, lane = tid & 63, wave = tid >> 6;
  int wr = wave >> 1, wc = wave & 1, lr = lane & 15;
  int ksub = (lane >> 4) * 8;
  int n0 = blockIdx.x * 64, m0 = blockIdx.y * 64;
  int lrow = tid >> 2, lq = tid & 3;

  f32x4 acc[2][2];
#pragma unroll
  for (int i = 0; i < 2; i++)
#pragma unroll
    for (int j = 0; j < 2; j++) acc[i][j] = (f32x4){0.f, 0.f, 0.f, 0.f};

  for (int k0 = 0; k0 < K; k0 += 64) {
    size_t aoff = (size_t)(m0 + lrow) * K + k0 + lq * 16;
    size_t boff = (size_t)(n0 + lrow) * K + k0 + lq * 16;
    int d0 = lrow * 64 + (((lq * 2) ^ (lrow & 7)) << 3);
    int d1 = lrow * 64 + (((lq * 2 + 1) ^ (lrow & 7)) << 3);
    *(ushort8v*)&AsH[d0] = *(const ushort8v*)&Ah[aoff];
    *(ushort8v*)&AsH[d1] = *(const ushort8v*)&Ah[aoff + 8];
    *(ushort8v*)&AsL[d0] = *(const ushort8v*)&Al[aoff];
    *(ushort8v*)&AsL[d1] = *(const ushort8v*)&Al[aoff + 8];
    *(ushort8v*)&BsH[d0] = *(const ushort8v*)&Bh[boff];
    *(ushort8v*)&BsH[d1] = *(const ushort8v*)&Bh[boff + 8];
    *(ushort8v*)&BsL[d0] = *(const ushort8v*)&Bl[boff];
    *(ushort8v*)&BsL[d1] = *(const ushort8v*)&Bl[boff + 8];
    __syncthreads();
#pragma unroll
    for (int kb = 0; kb < 2; kb++) {
      int kloc = kb * 32 + ksub;
      bf16x8 ah[2], al[2], bh[2], bl[2];
#pragma unroll
      for (int i = 0; i < 2; i++) {
        int m = wr * 32 + i * 16 + lr;
        int off = swz(m, kloc);
        ah[i] = *(const bf16x8*)&AsH[off];
        al[i] = *(const bf16x8*)&AsL[off];
      }
#pragma unroll
      for (int j = 0; j < 2; j++) {
        int n = wc * 32 + j * 16 + lr;
        int off = swz(n, kloc);
        bh[j] = *(const bf16x8*)&BsH[off];
        bl[j] = *(const bf16x8*)&BsL[off];
      }
#pragma unroll
      for (int i = 0; i < 2; i++)
#pragma unroll
        for (int j = 0; j < 2; j++) {
          acc[i][j] = __builtin_amdgcn_mfma_f32_16x16x32_bf16(ah[i], bh[j], acc[i][j], 0, 0, 0);
          acc[i][j] = __builtin_amdgcn_mfma_f32_16x16x32_bf16(ah[i], bl[j], acc[i][j], 0, 0, 0);
          acc[i][j] = __builtin_amdgcn_mfma_f32_16x16x32_bf16(al[i], bh[j], acc[i][j], 0, 0, 0);
        }
    }
    __syncthreads();
  }
#pragma unroll
  for (int i = 0; i < 2; i++)
#pragma unroll
    for (int j = 0; j < 2; j++) {
      int col = n0 + wc * 32 + j * 16 + lr;
      float bv = bias ? bias[col] : 0.f;
#pragma unroll
      for (int q = 0; q < 4; q++) {
        int row = m0 + wr * 32 + i * 16 + (lane >> 4) * 4 + q;
        float v = acc[i][j][q] + bv;
        if (act == 1) v = 0.5f * v * (1.f + erff(v * 0.70710678118654752f));
        if (Cf) {
          size_t off = seg ? (size_t)(col / CC) * NTCE + (size_t)row * CC + (col % CC)
                           : (size_t)row * N + col;
          Cf[off] = v;
        }
        if (Chi) {
          size_t o2 = (size_t)row * N + col;
          unsigned short hb, lb;
          split2(v, hb, lb);
          Chi[o2] = hb;
          Clo[o2] = lb;
        }
      }
    }
}

// ---------------- HOA score GEMM: scores[bh][t][s] = q_h[t,:] . K_h[s,:] ----------------
__global__ __launch_bounds__(256) void score_gemm_kernel(
    const float* __restrict__ qh, const float* __restrict__ K1, const float* __restrict__ K2,
    float* __restrict__ scores) {
  if (blockIdx.x > blockIdx.y) return;  // fully-masked (s > t) tile
  int bh = blockIdx.z;
  int br = bh >= HH ? 1 : 0;
  int h = bh - br * HH;
  const float* Kb = br ? K2 : K1;
  int s0 = blockIdx.x * 64, t0 = blockIdx.y * 64;
  int hDD = h * DD;
  __shared__ unsigned short AsH[64 * 64], AsL[64 * 64], BsH[64 * 64], BsL[64 * 64];
  int tid = threadIdx.x, lane = tid & 63, wave = tid >> 6;
  int wr = wave >> 1, wc = wave & 1, lr = lane & 15;
  int ksub = (lane >> 4) * 8;
  int lrow = tid >> 2, lq = tid & 3;
  {
    const float* srcA = qh + (size_t)(t0 + lrow) * CC + hDD + lq * 16;
    const float* srcB = Kb + (size_t)(s0 + lrow) * CC + hDD + lq * 16;
#pragma unroll
    for (int f = 0; f < 4; f++) {
      float4 va = *(const float4*)(srcA + f * 4);
      float4 vb = *(const float4*)(srcB + f * 4);
      int kk = lq * 16 + f * 4;
      int off = swz(lrow, kk);
      unsigned short h0, h1, h2, h3, l0, l1, l2, l3;
      split2(va.x, h0, l0); split2(va.y, h1, l1); split2(va.z, h2, l2); split2(va.w, h3, l3);
      *(ushort4*)&AsH[off] = make_ushort4(h0, h1, h2, h3);
      *(ushort4*)&AsL[off] = make_ushort4(l0, l1, l2, l3);
      split2(vb.x, h0, l0); split2(vb.y, h1, l1); split2(vb.z, h2, l2); split2(vb.w, h3, l3);
      *(ushort4*)&BsH[off] = make_ushort4(h0, h1, h2, h3);
      *(ushort4*)&BsL[off] = make_ushort4(l0, l1, l2, l3);
    }
  }
  __syncthreads();
  f32x4 acc[2][2];
#pragma unroll
  for (int i = 0; i < 2; i++)
#pragma unroll
    for (int j = 0; j < 2; j++) acc[i][j] = (f32x4){0.f, 0.f, 0.f, 0.f};
#pragma unroll
  for (int kb = 0; kb < 2; kb++) {
    int kloc = kb * 32 + ksub;
    bf16x8 ah[2], al[2], bh_[2], bl[2];
#pragma unroll
    for (int i = 0; i < 2; i++) {
      int m = wr * 32 + i * 16 + lr;
      int off = swz(m, kloc);
      ah[i] = *(const bf16x8*)&AsH[off];
      al[i] = *(const bf16x8*)&AsL[off];
    }
#pragma unroll
    for (int j = 0; j < 2; j++) {
      int n = wc * 32 + j * 16 + lr;
      int off = swz(n, kloc);
      bh_[j] = *(const bf16x8*)&BsH[off];
      bl[j] = *(const bf16x8*)&BsL[off];
    }
#pragma unroll
    for (int i = 0; i < 2; i++)
#pragma unroll
      for (int j = 0; j < 2; j++) {
        acc[i][j] = __builtin_amdgcn_mfma_f32_16x16x32_bf16(ah[i], bh_[j], acc[i][j], 0, 0, 0);
        acc[i][j] = __builtin_amdgcn_mfma_f32_16x16x32_bf16(ah[i], bl[j], acc[i][j], 0, 0, 0);
        acc[i][j] = __builtin_amdgcn_mfma_f32_16x16x32_bf16(al[i], bh_[j], acc[i][j], 0, 0, 0);
      }
  }
#pragma unroll
  for (int i = 0; i < 2; i++)
#pragma unroll
    for (int j = 0; j < 2; j++)
#pragma unroll
      for (int q = 0; q < 4; q++) {
        int tt = t0 + wr * 32 + i * 16 + (lane >> 4) * 4 + q;
        int ss = s0 + wc * 32 + j * 16 + lr;
        scores[((size_t)bh * TT + tt) * TT + ss] = acc[i][j][q];
      }
}

// ---------------- wave top-64 selection from precomputed score rows ----------------
__device__ __forceinline__ u64 cas_u64(u64 x, int j, bool dirmax, int lane) {
  u64 y = __shfl_xor(x, j);
  bool lower = (lane & j) == 0;
  bool keepmax = (dirmax == lower);
  return (keepmax ? (y > x) : (y < x)) ? y : x;
}
__device__ __forceinline__ u64 sort64_desc(u64 x, int lane) {
#pragma unroll
  for (int k = 2; k <= 64; k <<= 1) {
    bool dirmax = ((lane & k) == 0);
#pragma unroll
    for (int j = k >> 1; j; j >>= 1) x = cas_u64(x, j, dirmax, lane);
  }
  return x;
}
__device__ __forceinline__ u64 merge64_desc(u64 x, int lane) {
#pragma unroll
  for (int j = 32; j; j >>= 1) x = cas_u64(x, j, true, lane);
  return x;
}
__device__ __forceinline__ u64 make_key(float v, int s, int t) {
  unsigned sv = 0u;
  if (s <= t) {
    unsigned u = __float_as_uint(v);
    sv = (u & 0x80000000u) ? ~u : (u | 0x80000000u);
  }
  return ((u64)sv << 32) | (unsigned)(~s);
}

__global__ __launch_bounds__(256) void topk_select_kernel(
    const float* __restrict__ scores, int* __restrict__ idx1, int* __restrict__ idx2) {
  int tid = threadIdx.x, lane = tid & 63, w = tid >> 6;
  int row = blockIdx.x * 4 + w;  // 0..2*HH*TT-1
  int br = row >= (HH * TT) ? 1 : 0;
  int rem = row - br * (HH * TT);
  int h = rem >> 9, t = rem & (TT - 1);
  const float* sr = scores + ((size_t)(br * HH + h) * TT + t) * TT;
  u64 run = sort64_desc(make_key(sr[lane], lane, t), lane);
#pragma unroll
  for (int e = 1; e < 8; e++) {
    u64 kb = sort64_desc(make_key(sr[e * 64 + lane], e * 64 + lane, t), lane);
    u64 rev = __shfl(kb, 63 - lane);
    run = run > rev ? run : rev;
    run = merge64_desc(run, lane);
  }
  unsigned myidx = ~(unsigned)run;
  unsigned outv = __shfl(myidx, min(lane, t));  // clip/pad rule
  int* idxout = (br ? idx2 : idx1) + ((size_t)h * TT + t) * KKEEP;
  idxout[lane] = (int)outv;
}

// ---------------- causal SDPA (planes out) ----------------
__global__ void sdpa_kernel(const float* __restrict__ qkv,
                            unsigned short* __restrict__ yhi, unsigned short* __restrict__ ylo) {
  int h = blockIdx.x, t = blockIdx.y, tid = threadIdx.x;
  __shared__ float qv[DD];
  __shared__ float sc[TT];
  __shared__ float red[4];
  __shared__ float acc2[4][DD];
  if (tid < DD) qv[tid] = qkv[t * 3 * CC + h * DD + tid];
  __syncthreads();
  float lmax = -INFINITY;
  for (int s = tid; s <= t; s += 256) {
    const float* Kp = qkv + s * 3 * CC + CC + h * DD;
    float d = 0.f;
#pragma unroll
    for (int i = 0; i < DD; i++) d += qv[i] * Kp[i];
    d *= 0.125f;
    sc[s] = d;
    lmax = fmaxf(lmax, d);
  }
  {
#pragma unroll
    for (int off = 32; off; off >>= 1) lmax = fmaxf(lmax, __shfl_xor(lmax, off));
    __syncthreads();
    if ((tid & 63) == 0) red[tid >> 6] = lmax;
    __syncthreads();
    lmax = fmaxf(fmaxf(red[0], red[1]), fmaxf(red[2], red[3]));
  }
  float lsum = 0.f;
  for (int s = tid; s <= t; s += 256) { float e = expf(sc[s] - lmax); sc[s] = e; lsum += e; }
  float sum = block_sum(lsum, red);
  __syncthreads();
  int d = tid & 63, c = tid >> 6;
  float part = 0.f;
  for (int s = c; s <= t; s += 4) part += sc[s] * qkv[s * 3 * CC + 2 * CC + h * DD + d];
  acc2[c][d] = part;
  __syncthreads();
  if (tid < DD) {
    float tot = (acc2[0][tid] + acc2[1][tid] + acc2[2][tid] + acc2[3][tid]) / sum;
    unsigned short hb, lb;
    split2(tot, hb, lb);
    yhi[t * CC + h * DD + tid] = hb;
    ylo[t * CC + h * DD + tid] = lb;
  }
}

// ---------------- register bitonic sort of 512 u64 keys across one wave (gate) -------
__device__ __forceinline__ void sort512(u64* key, int lane) {
#pragma unroll
  for (int k = 2; k <= 512; k <<= 1) {
#pragma unroll
    for (int j = k >> 1; j > 0; j >>= 1) {
      if (j < 64) {
        bool lower = (lane & j) == 0;
#pragma unroll
        for (int e = 0; e < 8; e++) {
          bool desc = ((((e << 6) | lane) & k) == 0);
          u64 part = __shfl_xor(key[e], j);
          bool wantmax = (desc == lower);
          key[e] = (wantmax ? (part > key[e]) : (part < key[e])) ? part : key[e];
        }
      } else {
        int m = j >> 6;
#pragma unroll
        for (int e = 0; e < 8; e++) {
          if ((e & m) == 0) {
            int e2 = e | m;
            bool desc = ((((e << 6) | lane) & k) == 0);
            u64 a = key[e], b = key[e2];
            u64 mx = a > b ? a : b;
            u64 mn = a > b ? b : a;
            key[e] = desc ? mx : mn;
            key[e2] = desc ? mn : mx;
          }
        }
      }
    }
  }
}

// ---------------- HOA core: MFMA (per (h,t) block, 4 waves), planes out ----------------
__global__ __launch_bounds__(256) void hoa_core_kernel(
    const float* __restrict__ qh,
    const float* __restrict__ K1, const float* __restrict__ K2,
    const float* __restrict__ V1, const float* __restrict__ V2,
    const int* __restrict__ idx1, const int* __restrict__ idx2,
    unsigned short* __restrict__ hcohi, unsigned short* __restrict__ hcolo) {
  int h = blockIdx.x, t = blockIdx.y, tid = threadIdx.x;
  int lane = tid & 63, w = tid >> 6;
  int lr = lane & 15;
  int ksub = (lane >> 4) * 8;
  const int hDD = h * DD;

  __shared__ unsigned short bufA[64 * 64];
  __shared__ unsigned short bufB[64 * 64];
  __shared__ float v1s[64 * 65];
  __shared__ float red[4 * 64];

  const int* i1 = idx1 + (h * TT + t) * KKEEP;
  const int* i2 = idx2 + (h * TT + t) * KKEEP;

  float qreg = qh[t * CC + hDD + lane];

#pragma unroll
  for (int r = 0; r < 16; r++) {
    int j = w * 16 + r;
    int r1 = i1[j], r2 = i2[j];
    float k1v = K1[(size_t)r1 * CC + hDD + lane];
    float k2v = K2[(size_t)r2 * CC + hDD + lane];
    float v1v = V1[(size_t)r1 * CC + hDD + lane];
    int off = swz(j, lane);
    bufA[off] = f32_to_bf16_rne(k1v * qreg);
    bufB[off] = f32_to_bf16_rne(k2v);
    v1s[j * 65 + lane] = v1v;
  }
  __syncthreads();

  f32x4 acc[4];
#pragma unroll
  for (int nt = 0; nt < 4; nt++) acc[nt] = (f32x4){0.f, 0.f, 0.f, 0.f};
  {
    bf16x8 af[2];
#pragma unroll
    for (int kb = 0; kb < 2; kb++)
      af[kb] = *(const bf16x8*)&bufA[swz(w * 16 + lr, kb * 32 + ksub)];
#pragma unroll
    for (int nt = 0; nt < 4; nt++)
#pragma unroll
      for (int kb = 0; kb < 2; kb++) {
        bf16x8 bf = *(const bf16x8*)&bufB[swz(nt * 16 + lr, kb * 32 + ksub)];
        acc[nt] = __builtin_amdgcn_mfma_f32_16x16x32_bf16(af[kb], bf, acc[nt], 0, 0, 0);
      }
  }
#pragma unroll
  for (int q = 0; q < 4; q++) {
    float m = -INFINITY;
#pragma unroll
    for (int nt = 0; nt < 4; nt++) {
      acc[nt][q] *= 0.125f;
      m = fmaxf(m, acc[nt][q]);
    }
#pragma unroll
    for (int off = 1; off < 16; off <<= 1) m = fmaxf(m, __shfl_xor(m, off));
    float s = 0.f;
#pragma unroll
    for (int nt = 0; nt < 4; nt++) {
      float e = expf(acc[nt][q] - m);
      acc[nt][q] = e;
      s += e;
    }
#pragma unroll
    for (int off = 1; off < 16; off <<= 1) s += __shfl_xor(s, off);
    float inv = 1.f / s;
#pragma unroll
    for (int nt = 0; nt < 4; nt++) acc[nt][q] *= inv;
  }
  __syncthreads();

#pragma unroll
  for (int nt = 0; nt < 4; nt++)
#pragma unroll
    for (int q = 0; q < 4; q++) {
      int row = w * 16 + (lane >> 4) * 4 + q;
      int col = nt * 16 + lr;
      bufA[swz(row, col)] = f32_to_bf16_rne(acc[nt][q]);
    }
#pragma unroll
  for (int r = 0; r < 16; r++) {
    int k = w * 16 + r;
    float v2v = V2[(size_t)i2[k] * CC + hDD + lane];
    bufB[swz(lane, k)] = f32_to_bf16_rne(v2v);
  }
  __syncthreads();

  f32x4 acc2[4];
#pragma unroll
  for (int nt = 0; nt < 4; nt++) acc2[nt] = (f32x4){0.f, 0.f, 0.f, 0.f};
  {
    bf16x8 af[2];
#pragma unroll
    for (int kb = 0; kb < 2; kb++)
      af[kb] = *(const bf16x8*)&bufA[swz(w * 16 + lr, kb * 32 + ksub)];
#pragma unroll
    for (int nt = 0; nt < 4; nt++)
#pragma unroll
      for (int kb = 0; kb < 2; kb++) {
        bf16x8 bf = *(const bf16x8*)&bufB[swz(nt * 16 + lr, kb * 32 + ksub)];
        acc2[nt] = __builtin_amdgcn_mfma_f32_16x16x32_bf16(af[kb], bf, acc2[nt], 0, 0, 0);
      }
  }
#pragma unroll
  for (int nt = 0; nt < 4; nt++) {
    float p = 0.f;
#pragma unroll
    for (int q = 0; q < 4; q++) {
      int row = w * 16 + (lane >> 4) * 4 + q;
      int col = lr + 16 * nt;
      p += acc2[nt][q] * v1s[row * 65 + col];
    }
    p += __shfl_xor(p, 16);
    p += __shfl_xor(p, 32);
    if (lane < 16) red[w * 64 + 16 * nt + lr] = p;
  }
  __syncthreads();
  if (tid < 64) {
    float o = red[tid] + red[64 + tid] + red[128 + tid] + red[192 + tid];
    unsigned short hb, lb;
    split2(o, hb, lb);
    hcohi[t * CC + hDD + tid] = hb;
    hcolo[t * CC + hDD + tid] = lb;
  }
}

// ---------------- gate ----------------
__global__ void gate_scores_kernel(const float* __restrict__ hoin,
                                   const float* __restrict__ gw, const float* __restrict__ gb,
                                   float* __restrict__ scores) {
  int t = blockIdx.x, tid = threadIdx.x;
  __shared__ float red[4];
  float part = 0.f;
  for (int c = tid; c < CC; c += 256) part += hoin[t * CC + c] * gw[c];
  float s = block_sum(part, red);
  if (tid == 0) scores[t] = s + gb[0];
}

__global__ void gate_mask_kernel(const float* __restrict__ scores, float* __restrict__ mask) {
  int lane = threadIdx.x;  // 64 threads, one wave
  u64 key[8];
#pragma unroll
  for (int e = 0; e < 8; e++) {
    int s = e * 64 + lane;
    unsigned uu = __float_as_uint(scores[s]);
    unsigned sv = (uu & 0x80000000u) ? ~uu : (uu | 0x80000000u);
    key[e] = ((u64)sv << 32) | (unsigned)(~s);
    mask[s] = 0.f;
  }
  __asm__ volatile("s_waitcnt vmcnt(0)" ::: "memory");
  sort512(key, lane);
#pragma unroll
  for (int e = 0; e < 2; e++) mask[(int)(~(unsigned)key[e])] = 1.f;
}

// ---------------- elementwise ----------------
__global__ void add_kernel(const float* __restrict__ a, const float* __restrict__ b,
                           float* __restrict__ o, int n) {
  int i = blockIdx.x * 256 + threadIdx.x;
  if (i < n) o[i] = a[i] + b[i];
}

__global__ void masked_add_kernel(const float* __restrict__ a, const float* __restrict__ b,
                                  const float* __restrict__ mask, float* __restrict__ o, int n) {
  int i = blockIdx.x * 256 + threadIdx.x;
  if (i < n) o[i] = a[i] + b[i] * mask[i / CC];
}

// ---------------- launcher ----------------
extern "C" void kernel_launch(void* const* d_in, const int* in_sizes, int n_in,
                              void* d_out, int out_size, void* d_ws, size_t ws_size,
                              hipStream_t stream) {
  const float* x      = (const float*)d_in[0];
  const float* ln1_w  = (const float*)d_in[1];
  const float* ln1_b  = (const float*)d_in[2];
  const float* qkv_w  = (const float*)d_in[3];
  const float* qkv_b  = (const float*)d_in[4];
  const float* atto_w = (const float*)d_in[5];
  const float* atto_b = (const float*)d_in[6];
  const float* lnh_w  = (const float*)d_in[7];
  const float* lnh_b  = (const float*)d_in[8];
  const float* hq_w   = (const float*)d_in[9];
  const float* hk1_w  = (const float*)d_in[10];
  const float* hk2_w  = (const float*)d_in[11];
  const float* hv1_w  = (const float*)d_in[12];
  const float* hv2_w  = (const float*)d_in[13];
  const float* ho_w   = (const float*)d_in[14];
  const float* gate_w = (const float*)d_in[15];
  const float* gate_b = (const float*)d_in[16];
  const float* ln2_w  = (const float*)d_in[17];
  const float* ln2_b  = (const float*)d_in[18];
  const float* fc_w   = (const float*)d_in[19];
  const float* fc_b   = (const float*)d_in[20];
  const float* pr_w   = (const float*)d_in[21];
  const float* pr_b   = (const float*)d_in[22];
  float* out = (float*)d_out;

  // workspace carve-up
  char* cur = (char*)d_ws;
  auto alloc = [&](size_t bytes) {
    char* p = cur;
    cur += (bytes + 255) & ~(size_t)255;
    return p;
  };
  float* qkv  = (float*)alloc((size_t)3 * NTCE * 4);
  float* x1   = (float*)alloc((size_t)NTCE * 4);
  float* hoin = (float*)alloc((size_t)NTCE * 4);
  float* qh   = (float*)alloc((size_t)5 * NTCE * 4);  // qh,K1,K2,V1,V2 contiguous
  float* K1   = qh + NTCE;
  float* K2   = K1 + NTCE;
  float* V1   = K2 + NTCE;
  float* V2   = V1 + NTCE;
  float* hout = (float*)alloc((size_t)NTCE * 4);
  float* x2   = (float*)alloc((size_t)NTCE * 4);
  float* tmp  = (float*)alloc((size_t)NTCE * 4);
  float* scores = (float*)alloc(TT * 4);
  float* maskb  = (float*)alloc(TT * 4);
  int* idx1 = (int*)alloc((size_t)HH * TT * KKEEP * 4);
  int* idx2 = (int*)alloc((size_t)HH * TT * KKEEP * 4);
  float* hscores = (float*)alloc((size_t)2 * HH * TT * TT * 4);  // 25 MB
  // activation planes
  unsigned short* hHi    = (unsigned short*)alloc((size_t)NTCE * 2);
  unsigned short* hLo    = (unsigned short*)alloc((size_t)NTCE * 2);
  unsigned short* yHi    = (unsigned short*)alloc((size_t)NTCE * 2);
  unsigned short* yLo    = (unsigned short*)alloc((size_t)NTCE * 2);
  unsigned short* hoinHi = (unsigned short*)alloc((size_t)NTCE * 2);
  unsigned short* hoinLo = (unsigned short*)alloc((size_t)NTCE * 2);
  unsigned short* h2Hi   = (unsigned short*)alloc((size_t)NTCE * 2);
  unsigned short* h2Lo   = (unsigned short*)alloc((size_t)NTCE * 2);
  unsigned short* hcoHi  = (unsigned short*)alloc((size_t)NTCE * 2);
  unsigned short* hcoLo  = (unsigned short*)alloc((size_t)NTCE * 2);
  unsigned short* fcbHi  = (unsigned short*)alloc((size_t)4 * NTCE * 2);
  unsigned short* fcbLo  = (unsigned short*)alloc((size_t)4 * NTCE * 2);
  // weight planes (transposed [N][K])
  const size_t WSQ = (size_t)CC * CC;
  unsigned short* qkvT_h = (unsigned short*)alloc((size_t)CC * 3 * CC * 2);
  unsigned short* qkvT_l = (unsigned short*)alloc((size_t)CC * 3 * CC * 2);
  unsigned short* attoT_h = (unsigned short*)alloc(WSQ * 2);
  unsigned short* attoT_l = (unsigned short*)alloc(WSQ * 2);
  unsigned short* hoaT_h = (unsigned short*)alloc(5 * WSQ * 2);
  unsigned short* hoaT_l = (unsigned short*)alloc(5 * WSQ * 2);
  unsigned short* hoT_h = (unsigned short*)alloc(WSQ * 2);
  unsigned short* hoT_l = (unsigned short*)alloc(WSQ * 2);
  unsigned short* fcT_h = (unsigned short*)alloc((size_t)CC * 4 * CC * 2);
  unsigned short* fcT_l = (unsigned short*)alloc((size_t)CC * 4 * CC * 2);
  unsigned short* prT_h = (unsigned short*)alloc((size_t)CC * 4 * CC * 2);
  unsigned short* prT_l = (unsigned short*)alloc((size_t)CC * 4 * CC * 2);

  // weight split jobs
  WSplitArgs wa;
  int tcur = 0;
  auto addw = [&](int i, const float* s, unsigned short* hi, unsigned short* lo, int K, int N) {
    wa.src[i] = s; wa.hi[i] = hi; wa.lo[i] = lo;
    wa.K[i] = K; wa.N[i] = N; wa.tstart[i] = tcur;
    tcur += (N / 64) * (K / 64);
  };
  addw(0, qkv_w, qkvT_h, qkvT_l, CC, 3 * CC);
  addw(1, atto_w, attoT_h, attoT_l, CC, CC);
  addw(2, hq_w,  hoaT_h + 0 * WSQ, hoaT_l + 0 * WSQ, CC, CC);
  addw(3, hk1_w, hoaT_h + 1 * WSQ, hoaT_l + 1 * WSQ, CC, CC);
  addw(4, hk2_w, hoaT_h + 2 * WSQ, hoaT_l + 2 * WSQ, CC, CC);
  addw(5, hv1_w, hoaT_h + 3 * WSQ, hoaT_l + 3 * WSQ, CC, CC);
  addw(6, hv2_w, hoaT_h + 4 * WSQ, hoaT_l + 4 * WSQ, CC, CC);
  addw(7, ho_w, hoT_h, hoT_l, CC, CC);
  addw(8, fc_w, fcT_h, fcT_l, CC, 4 * CC);
  addw(9, pr_w, prT_h, prT_l, 4 * CC, CC);

  dim3 blk(256);
  int nElem = NTCE;
  int nBlocks = (nElem + 255) / 256;

  hipLaunchKernelGGL(wsplitT_kernel, dim3(tcur), blk, 0, stream, wa);
  // LN1 -> h planes
  hipLaunchKernelGGL(ln_bf_kernel, dim3(TT), blk, 0, stream, x, ln1_w, ln1_b,
                     (float*)nullptr, hHi, hLo);
  // QKV
  hipLaunchKernelGGL(gemm_bf, dim3(36, 8), blk, 0, stream, hHi, hLo, qkvT_h, qkvT_l,
                     qkv_b, qkv, (unsigned short*)nullptr, (unsigned short*)nullptr,
                     TT, 3 * CC, CC, 0, 0);
  // SDPA -> y planes
  hipLaunchKernelGGL(sdpa_kernel, dim3(HH, TT), blk, 0, stream, qkv, yHi, yLo);
  // atto -> tmp
  hipLaunchKernelGGL(gemm_bf, dim3(12, 8), blk, 0, stream, yHi, yLo, attoT_h, attoT_l,
                     atto_b, tmp, (unsigned short*)nullptr, (unsigned short*)nullptr,
                     TT, CC, CC, 0, 0);
  hipLaunchKernelGGL(add_kernel, dim3(nBlocks), blk, 0, stream, x, tmp, x1, nElem);
  // LNh -> hoin f32 + planes
  hipLaunchKernelGGL(ln_bf_kernel, dim3(TT), blk, 0, stream, x1, lnh_w, lnh_b,
                     hoin, hoinHi, hoinLo);
  // 5 HOA projections merged (N=3840, segmented out to qh..V2)
  hipLaunchKernelGGL(gemm_bf, dim3(60, 8), blk, 0, stream, hoinHi, hoinLo, hoaT_h, hoaT_l,
                     (const float*)nullptr, qh, (unsigned short*)nullptr, (unsigned short*)nullptr,
                     TT, 5 * CC, CC, 0, 1);
  // HOA scores (both branches) + wave top-64 selection
  hipLaunchKernelGGL(score_gemm_kernel, dim3(8, 8, 2 * HH), blk, 0, stream,
                     qh, K1, K2, hscores);
  hipLaunchKernelGGL(topk_select_kernel, dim3(2 * HH * TT / 4), blk, 0, stream,
                     hscores, idx1, idx2);
  // HOA core -> hco planes
  hipLaunchKernelGGL(hoa_core_kernel, dim3(HH, TT), blk, 0, stream,
                     qh, K1, K2, V1, V2, idx1, idx2, hcoHi, hcoLo);
  // ho -> hout
  hipLaunchKernelGGL(gemm_bf, dim3(12, 8), blk, 0, stream, hcoHi, hcoLo, hoT_h, hoT_l,
                     (const float*)nullptr, hout, (unsigned short*)nullptr, (unsigned short*)nullptr,
                     TT, CC, CC, 0, 0);
  // gate
  hipLaunchKernelGGL(gate_scores_kernel, dim3(TT), blk, 0, stream, hoin, gate_w, gate_b, scores);
  hipLaunchKernelGGL(gate_mask_kernel, dim3(1), dim3(64), 0, stream, scores, maskb);
  hipLaunchKernelGGL(masked_add_kernel, dim3(nBlocks), blk, 0, stream, x1, hout, maskb, x2, nElem);
  // LN2 -> h2 planes
  hipLaunchKernelGGL(ln_bf_kernel, dim3(TT), blk, 0, stream, x2, ln2_w, ln2_b,
                     (float*)nullptr, h2Hi, h2Lo);
  // fc (+gelu) -> fcb planes
  hipLaunchKernelGGL(gemm_bf, dim3(48, 8), blk, 0, stream, h2Hi, h2Lo, fcT_h, fcT_l,
                     fc_b, (float*)nullptr, fcbHi, fcbLo, TT, 4 * CC, CC, 1, 0);
  // pr -> tmp
  hipLaunchKernelGGL(gemm_bf, dim3(12, 8), blk, 0, stream, fcbHi, fcbLo, prT_h, prT_l,
                     pr_b, tmp, (unsigned short*)nullptr, (unsigned short*)nullptr,
                     TT, CC, 4 * CC, 0, 0);
  hipLaunchKernelGGL(add_kernel, dim3(nBlocks), blk, 0, stream, x2, tmp, out, nElem);
}

// Round 6
// 375.073 us; speedup vs baseline: 2.2209x; 1.0891x over previous
//
#include <hip/hip_runtime.h>
#include <hip/hip_bf16.h>
#include <math.h>

#define TT 512
#define CC 768
#define HH 12
#define DD 64
#define KKEEP 64
#define TOPG 128
#define NTCE (TT * CC)

typedef __attribute__((ext_vector_type(8))) short bf16x8;
typedef __attribute__((ext_vector_type(8))) unsigned short ushort8v;
typedef __attribute__((ext_vector_type(4))) float f32x4;
typedef unsigned long long u64;

// ---------------- helpers ----------------
__device__ __forceinline__ float block_sum(float v, float* red) {
#pragma unroll
  for (int off = 32; off; off >>= 1) v += __shfl_xor(v, off);
  __syncthreads();
  if ((threadIdx.x & 63) == 0) red[threadIdx.x >> 6] = v;
  __syncthreads();
  return red[0] + red[1] + red[2] + red[3];
}

__device__ __forceinline__ unsigned short f32_to_bf16_rne(float f) {
  unsigned u = __float_as_uint(f);
  unsigned r = (u + 0x7FFFu + ((u >> 16) & 1u)) >> 16;
  return (unsigned short)r;
}
__device__ __forceinline__ float bf16_to_f32(unsigned short h) {
  return __uint_as_float(((unsigned)h) << 16);
}
__device__ __forceinline__ void split2(float x, unsigned short& h, unsigned short& l) {
  h = f32_to_bf16_rne(x);
  l = f32_to_bf16_rne(x - bf16_to_f32(h));
}
__device__ __forceinline__ int swz(int row, int k) {
  return row * 64 + ((((k >> 3) ^ (row & 7))) << 3) + (k & 7);
}

// ---------------- weight split+transpose (all 10 weights, one dispatch) ----------------
struct WSplitArgs {
  const float* src[10];
  unsigned short* hi[10];
  unsigned short* lo[10];
  int K[10], N[10], tstart[10];
};

__global__ __launch_bounds__(256) void wsplitT_kernel(WSplitArgs a) {
  __shared__ float tile_[64][65];
  int t = blockIdx.x;
  int wsel = 0;
#pragma unroll
  for (int i = 1; i < 10; i++)
    if (t >= a.tstart[i]) wsel = i;
  int local = t - a.tstart[wsel];
  int K = a.K[wsel], N = a.N[wsel];
  int ntn = N >> 6;
  int bn = local % ntn, bk = local / ntn;
  int tid = threadIdx.x, r = tid >> 2, cq = tid & 3;
  const float* src = a.src[wsel] + (size_t)(bk * 64 + r) * N + bn * 64 + cq * 16;
#pragma unroll
  for (int f = 0; f < 4; f++) {
    float4 v = *(const float4*)(src + f * 4);
    tile_[r][cq * 16 + f * 4 + 0] = v.x;
    tile_[r][cq * 16 + f * 4 + 1] = v.y;
    tile_[r][cq * 16 + f * 4 + 2] = v.z;
    tile_[r][cq * 16 + f * 4 + 3] = v.w;
  }
  __syncthreads();
  size_t dst = (size_t)(bn * 64 + r) * K + bk * 64 + cq * 16;
  unsigned short hv[16], lv[16];
#pragma unroll
  for (int i = 0; i < 16; i++) split2(tile_[cq * 16 + i][r], hv[i], lv[i]);
  *(ushort8v*)&a.hi[wsel][dst] = *(const ushort8v*)&hv[0];
  *(ushort8v*)&a.hi[wsel][dst + 8] = *(const ushort8v*)&hv[8];
  *(ushort8v*)&a.lo[wsel][dst] = *(const ushort8v*)&lv[0];
  *(ushort8v*)&a.lo[wsel][dst + 8] = *(const ushort8v*)&lv[8];
}

// ---------------- layernorm (f32 out optional, split-bf16 planes out) ----------------
__global__ void ln_bf_kernel(const float* __restrict__ x, const float* __restrict__ w,
                             const float* __restrict__ b, float* __restrict__ outf,
                             unsigned short* __restrict__ ohi, unsigned short* __restrict__ olo) {
  int t = blockIdx.x, tid = threadIdx.x;
  __shared__ float red[4];
  float ls = 0.f;
  for (int c = tid; c < CC; c += 256) ls += x[t * CC + c];
  float mean = block_sum(ls, red) * (1.f / CC);
  float lv = 0.f;
  for (int c = tid; c < CC; c += 256) { float d = x[t * CC + c] - mean; lv += d * d; }
  float var = block_sum(lv, red) * (1.f / CC);
  float rs = rsqrtf(var + 1e-5f);
  for (int c = tid; c < CC; c += 256) {
    float val = (x[t * CC + c] - mean) * rs * w[c] + b[c];
    if (outf) outf[t * CC + c] = val;
    unsigned short hb, lb;
    split2(val, hb, lb);
    ohi[t * CC + c] = hb;
    olo[t * CC + c] = lb;
  }
}

// ---------------- split-bf16 MFMA GEMM from preconverted planes ----------------
__global__ __launch_bounds__(256) void gemm_bf(
    const unsigned short* __restrict__ Ah, const unsigned short* __restrict__ Al,
    const unsigned short* __restrict__ Bh, const unsigned short* __restrict__ Bl,
    const float* __restrict__ bias, float* __restrict__ Cf,
    unsigned short* __restrict__ Chi, unsigned short* __restrict__ Clo,
    int M, int N, int K, int act, int seg, const float* __restrict__ res) {
  __shared__ unsigned short AsH[64 * 64], AsL[64 * 64], BsH[64 * 64], BsL[64 * 64];
  int tid = threadIdx.x, lane = tid & 63, wave = tid >> 6;
  int wr = wave >> 1, wc = wave & 1, lr = lane & 15;
  int ksub = (lane >> 4) * 8;
  int n0 = blockIdx.x * 64, m0 = blockIdx.y * 64;
  int lrow = tid >> 2, lq = tid & 3;

  f32x4 acc[2][2];
#pragma unroll
  for (int i = 0; i < 2; i++)
#pragma unroll
    for (int j = 0; j < 2; j++) acc[i][j] = (f32x4){0.f, 0.f, 0.f, 0.f};

  for (int k0 = 0; k0 < K; k0 += 64) {
    size_t aoff = (size_t)(m0 + lrow) * K + k0 + lq * 16;
    size_t boff = (size_t)(n0 + lrow) * K + k0 + lq * 16;
    int d0 = lrow * 64 + (((lq * 2) ^ (lrow & 7)) << 3);
    int d1 = lrow * 64 + (((lq * 2 + 1) ^ (lrow & 7)) << 3);
    *(ushort8v*)&AsH[d0] = *(const ushort8v*)&Ah[aoff];
    *(ushort8v*)&AsH[d1] = *(const ushort8v*)&Ah[aoff + 8];
    *(ushort8v*)&AsL[d0] = *(const ushort8v*)&Al[aoff];
    *(ushort8v*)&AsL[d1] = *(const ushort8v*)&Al[aoff + 8];
    *(ushort8v*)&BsH[d0] = *(const ushort8v*)&Bh[boff];
    *(ushort8v*)&BsH[d1] = *(const ushort8v*)&Bh[boff + 8];
    *(ushort8v*)&BsL[d0] = *(const ushort8v*)&Bl[boff];
    *(ushort8v*)&BsL[d1] = *(const ushort8v*)&Bl[boff + 8];
    __syncthreads();
#pragma unroll
    for (int kb = 0; kb < 2; kb++) {
      int kloc = kb * 32 + ksub;
      bf16x8 ah[2], al[2], bh[2], bl[2];
#pragma unroll
      for (int i = 0; i < 2; i++) {
        int m = wr * 32 + i * 16 + lr;
        int off = swz(m, kloc);
        ah[i] = *(const bf16x8*)&AsH[off];
        al[i] = *(const bf16x8*)&AsL[off];
      }
#pragma unroll
      for (int j = 0; j < 2; j++) {
        int n = wc * 32 + j * 16 + lr;
        int off = swz(n, kloc);
        bh[j] = *(const bf16x8*)&BsH[off];
        bl[j] = *(const bf16x8*)&BsL[off];
      }
#pragma unroll
      for (int i = 0; i < 2; i++)
#pragma unroll
        for (int j = 0; j < 2; j++) {
          acc[i][j] = __builtin_amdgcn_mfma_f32_16x16x32_bf16(ah[i], bh[j], acc[i][j], 0, 0, 0);
          acc[i][j] = __builtin_amdgcn_mfma_f32_16x16x32_bf16(ah[i], bl[j], acc[i][j], 0, 0, 0);
          acc[i][j] = __builtin_amdgcn_mfma_f32_16x16x32_bf16(al[i], bh[j], acc[i][j], 0, 0, 0);
        }
    }
    __syncthreads();
  }
#pragma unroll
  for (int i = 0; i < 2; i++)
#pragma unroll
    for (int j = 0; j < 2; j++) {
      int col = n0 + wc * 32 + j * 16 + lr;
      float bv = bias ? bias[col] : 0.f;
#pragma unroll
      for (int q = 0; q < 4; q++) {
        int row = m0 + wr * 32 + i * 16 + (lane >> 4) * 4 + q;
        float v = acc[i][j][q] + bv;
        if (act == 1) v = 0.5f * v * (1.f + erff(v * 0.70710678118654752f));
        if (Cf) {
          size_t off = seg ? (size_t)(col / CC) * NTCE + (size_t)row * CC + (col % CC)
                           : (size_t)row * N + col;
          if (res) v += res[off];
          Cf[off] = v;
        }
        if (Chi) {
          size_t o2 = (size_t)row * N + col;
          unsigned short hb, lb;
          split2(v, hb, lb);
          Chi[o2] = hb;
          Clo[o2] = lb;
        }
      }
    }
}

// ---------------- flash-style MFMA SDPA (per (h, 64-row t-tile), planes out) ----------
__global__ __launch_bounds__(256) void sdpa_mfma_kernel(
    const float* __restrict__ qkv,
    unsigned short* __restrict__ yhi, unsigned short* __restrict__ ylo) {
  int h = blockIdx.x, bt = blockIdx.y;
  int t0 = bt * 64;
  int tid = threadIdx.x, lane = tid & 63, w = tid >> 6;
  int lr = lane & 15, ksub = (lane >> 4) * 8;
  const int hDD = h * DD;

  __shared__ unsigned short qHi[64 * 64], qLo[64 * 64];
  __shared__ unsigned short kHi[64 * 64], kLo[64 * 64];
  __shared__ unsigned short bufP[64 * 64], bufV[64 * 64];

  int lrow = tid >> 2, lq = tid & 3;
  // stage Q tile once (split)
  {
    const float* src = qkv + (size_t)(t0 + lrow) * (3 * CC) + hDD + lq * 16;
#pragma unroll
    for (int f = 0; f < 4; f++) {
      float4 v = *(const float4*)(src + f * 4);
      int kk = lq * 16 + f * 4;
      int off = swz(lrow, kk);
      unsigned short h0, h1, h2, h3, l0, l1, l2, l3;
      split2(v.x, h0, l0); split2(v.y, h1, l1); split2(v.z, h2, l2); split2(v.w, h3, l3);
      *(ushort4*)&qHi[off] = make_ushort4(h0, h1, h2, h3);
      *(ushort4*)&qLo[off] = make_ushort4(l0, l1, l2, l3);
    }
  }

  float m[4], l[4];
  f32x4 o[4];
#pragma unroll
  for (int q = 0; q < 4; q++) { m[q] = -INFINITY; l[q] = 0.f; }
#pragma unroll
  for (int nt = 0; nt < 4; nt++) o[nt] = (f32x4){0.f, 0.f, 0.f, 0.f};

  for (int st = 0; st <= bt; st++) {
    int s0 = st * 64;
    __syncthreads();  // protect kHi/kLo/bufV/bufP reuse
    {
      const float* src = qkv + (size_t)(s0 + lrow) * (3 * CC) + CC + hDD + lq * 16;
#pragma unroll
      for (int f = 0; f < 4; f++) {
        float4 v = *(const float4*)(src + f * 4);
        int kk = lq * 16 + f * 4;
        int off = swz(lrow, kk);
        unsigned short h0, h1, h2, h3, l0, l1, l2, l3;
        split2(v.x, h0, l0); split2(v.y, h1, l1); split2(v.z, h2, l2); split2(v.w, h3, l3);
        *(ushort4*)&kHi[off] = make_ushort4(h0, h1, h2, h3);
        *(ushort4*)&kLo[off] = make_ushort4(l0, l1, l2, l3);
      }
    }
#pragma unroll
    for (int r = 0; r < 16; r++) {
      int sl = w * 16 + r;
      float v = qkv[(size_t)(s0 + sl) * (3 * CC) + 2 * CC + hDD + lane];
      bufV[swz(lane, sl)] = f32_to_bf16_rne(v);
    }
    __syncthreads();
    // S = Q K^T (split-bf16, 3 MFMA)
    f32x4 acc[4];
#pragma unroll
    for (int nt = 0; nt < 4; nt++) acc[nt] = (f32x4){0.f, 0.f, 0.f, 0.f};
    {
      bf16x8 ah[2], al[2];
#pragma unroll
      for (int kb = 0; kb < 2; kb++) {
        int off = swz(w * 16 + lr, kb * 32 + ksub);
        ah[kb] = *(const bf16x8*)&qHi[off];
        al[kb] = *(const bf16x8*)&qLo[off];
      }
#pragma unroll
      for (int nt = 0; nt < 4; nt++)
#pragma unroll
        for (int kb = 0; kb < 2; kb++) {
          int off = swz(nt * 16 + lr, kb * 32 + ksub);
          bf16x8 bh = *(const bf16x8*)&kHi[off];
          bf16x8 bl = *(const bf16x8*)&kLo[off];
          acc[nt] = __builtin_amdgcn_mfma_f32_16x16x32_bf16(ah[kb], bh, acc[nt], 0, 0, 0);
          acc[nt] = __builtin_amdgcn_mfma_f32_16x16x32_bf16(ah[kb], bl, acc[nt], 0, 0, 0);
          acc[nt] = __builtin_amdgcn_mfma_f32_16x16x32_bf16(al[kb], bh, acc[nt], 0, 0, 0);
        }
    }
    // online softmax update (per q-row; row group = 16 lanes sharing lane>>4)
#pragma unroll
    for (int q = 0; q < 4; q++) {
      int trow = t0 + w * 16 + (lane >> 4) * 4 + q;
      float tm = -INFINITY;
#pragma unroll
      for (int nt = 0; nt < 4; nt++) {
        float v = acc[nt][q] * 0.125f;
        if (s0 + nt * 16 + lr > trow) v = -INFINITY;
        acc[nt][q] = v;
        tm = fmaxf(tm, v);
      }
#pragma unroll
      for (int off = 1; off < 16; off <<= 1) tm = fmaxf(tm, __shfl_xor(tm, off));
      float mn = fmaxf(m[q], tm);
      float scale = expf(m[q] - mn);
      float ps = 0.f;
#pragma unroll
      for (int nt = 0; nt < 4; nt++) {
        float e = expf(acc[nt][q] - mn);
        acc[nt][q] = e;
        ps += e;
      }
#pragma unroll
      for (int off = 1; off < 16; off <<= 1) ps += __shfl_xor(ps, off);
      l[q] = l[q] * scale + ps;
      m[q] = mn;
#pragma unroll
      for (int nt = 0; nt < 4; nt++) o[nt][q] *= scale;
    }
    // write P (bf16) to LDS
#pragma unroll
    for (int nt = 0; nt < 4; nt++)
#pragma unroll
      for (int q = 0; q < 4; q++) {
        int row = w * 16 + (lane >> 4) * 4 + q;
        int col = nt * 16 + lr;
        bufP[swz(row, col)] = f32_to_bf16_rne(acc[nt][q]);
      }
    __syncthreads();
    // O += P V^T
    {
      bf16x8 pf[2];
#pragma unroll
      for (int kb = 0; kb < 2; kb++)
        pf[kb] = *(const bf16x8*)&bufP[swz(w * 16 + lr, kb * 32 + ksub)];
#pragma unroll
      for (int nt = 0; nt < 4; nt++)
#pragma unroll
        for (int kb = 0; kb < 2; kb++) {
          bf16x8 bv = *(const bf16x8*)&bufV[swz(nt * 16 + lr, kb * 32 + ksub)];
          o[nt] = __builtin_amdgcn_mfma_f32_16x16x32_bf16(pf[kb], bv, o[nt], 0, 0, 0);
        }
    }
  }
  // epilogue: y = O / l
#pragma unroll
  for (int nt = 0; nt < 4; nt++)
#pragma unroll
    for (int q = 0; q < 4; q++) {
      int trow = t0 + w * 16 + (lane >> 4) * 4 + q;
      int d = nt * 16 + lr;
      float v = o[nt][q] / l[q];
      unsigned short hb, lb;
      split2(v, hb, lb);
      yhi[(size_t)trow * CC + hDD + d] = hb;
      ylo[(size_t)trow * CC + hDD + d] = lb;
    }
}

// ---------------- HOA score GEMM: scores[bh][t][s] = q_h[t,:] . K_h[s,:] ----------------
__global__ __launch_bounds__(256) void score_gemm_kernel(
    const float* __restrict__ qh, const float* __restrict__ K1, const float* __restrict__ K2,
    float* __restrict__ scores) {
  if (blockIdx.x > blockIdx.y) return;
  int bh = blockIdx.z;
  int br = bh >= HH ? 1 : 0;
  int h = bh - br * HH;
  const float* Kb = br ? K2 : K1;
  int s0 = blockIdx.x * 64, t0 = blockIdx.y * 64;
  int hDD = h * DD;
  __shared__ unsigned short AsH[64 * 64], AsL[64 * 64], BsH[64 * 64], BsL[64 * 64];
  int tid = threadIdx.x, lane = tid & 63, wave = tid >> 6;
  int wr = wave >> 1, wc = wave & 1, lr = lane & 15;
  int ksub = (lane >> 4) * 8;
  int lrow = tid >> 2, lq = tid & 3;
  {
    const float* srcA = qh + (size_t)(t0 + lrow) * CC + hDD + lq * 16;
    const float* srcB = Kb + (size_t)(s0 + lrow) * CC + hDD + lq * 16;
#pragma unroll
    for (int f = 0; f < 4; f++) {
      float4 va = *(const float4*)(srcA + f * 4);
      float4 vb = *(const float4*)(srcB + f * 4);
      int kk = lq * 16 + f * 4;
      int off = swz(lrow, kk);
      unsigned short h0, h1, h2, h3, l0, l1, l2, l3;
      split2(va.x, h0, l0); split2(va.y, h1, l1); split2(va.z, h2, l2); split2(va.w, h3, l3);
      *(ushort4*)&AsH[off] = make_ushort4(h0, h1, h2, h3);
      *(ushort4*)&AsL[off] = make_ushort4(l0, l1, l2, l3);
      split2(vb.x, h0, l0); split2(vb.y, h1, l1); split2(vb.z, h2, l2); split2(vb.w, h3, l3);
      *(ushort4*)&BsH[off] = make_ushort4(h0, h1, h2, h3);
      *(ushort4*)&BsL[off] = make_ushort4(l0, l1, l2, l3);
    }
  }
  __syncthreads();
  f32x4 acc[2][2];
#pragma unroll
  for (int i = 0; i < 2; i++)
#pragma unroll
    for (int j = 0; j < 2; j++) acc[i][j] = (f32x4){0.f, 0.f, 0.f, 0.f};
#pragma unroll
  for (int kb = 0; kb < 2; kb++) {
    int kloc = kb * 32 + ksub;
    bf16x8 ah[2], al[2], bh_[2], bl[2];
#pragma unroll
    for (int i = 0; i < 2; i++) {
      int m = wr * 32 + i * 16 + lr;
      int off = swz(m, kloc);
      ah[i] = *(const bf16x8*)&AsH[off];
      al[i] = *(const bf16x8*)&AsL[off];
    }
#pragma unroll
    for (int j = 0; j < 2; j++) {
      int n = wc * 32 + j * 16 + lr;
      int off = swz(n, kloc);
      bh_[j] = *(const bf16x8*)&BsH[off];
      bl[j] = *(const bf16x8*)&BsL[off];
    }
#pragma unroll
    for (int i = 0; i < 2; i++)
#pragma unroll
      for (int j = 0; j < 2; j++) {
        acc[i][j] = __builtin_amdgcn_mfma_f32_16x16x32_bf16(ah[i], bh_[j], acc[i][j], 0, 0, 0);
        acc[i][j] = __builtin_amdgcn_mfma_f32_16x16x32_bf16(ah[i], bl[j], acc[i][j], 0, 0, 0);
        acc[i][j] = __builtin_amdgcn_mfma_f32_16x16x32_bf16(al[i], bh_[j], acc[i][j], 0, 0, 0);
      }
  }
#pragma unroll
  for (int i = 0; i < 2; i++)
#pragma unroll
    for (int j = 0; j < 2; j++)
#pragma unroll
      for (int q = 0; q < 4; q++) {
        int tt = t0 + wr * 32 + i * 16 + (lane >> 4) * 4 + q;
        int ss = s0 + wc * 32 + j * 16 + lr;
        scores[((size_t)bh * TT + tt) * TT + ss] = acc[i][j][q];
      }
}

// ---------------- wave top-64 selection from precomputed score rows ----------------
__device__ __forceinline__ u64 cas_u64(u64 x, int j, bool dirmax, int lane) {
  u64 y = __shfl_xor(x, j);
  bool lower = (lane & j) == 0;
  bool keepmax = (dirmax == lower);
  return (keepmax ? (y > x) : (y < x)) ? y : x;
}
__device__ __forceinline__ u64 sort64_desc(u64 x, int lane) {
#pragma unroll
  for (int k = 2; k <= 64; k <<= 1) {
    bool dirmax = ((lane & k) == 0);
#pragma unroll
    for (int j = k >> 1; j; j >>= 1) x = cas_u64(x, j, dirmax, lane);
  }
  return x;
}
__device__ __forceinline__ u64 merge64_desc(u64 x, int lane) {
#pragma unroll
  for (int j = 32; j; j >>= 1) x = cas_u64(x, j, true, lane);
  return x;
}
__device__ __forceinline__ u64 make_key(float v, int s, int t) {
  unsigned sv = 0u;
  if (s <= t) {
    unsigned u = __float_as_uint(v);
    sv = (u & 0x80000000u) ? ~u : (u | 0x80000000u);
  }
  return ((u64)sv << 32) | (unsigned)(~s);
}

__global__ __launch_bounds__(256) void topk_select_kernel(
    const float* __restrict__ scores, int* __restrict__ idx1, int* __restrict__ idx2) {
  int tid = threadIdx.x, lane = tid & 63, w = tid >> 6;
  int row = blockIdx.x * 4 + w;
  int br = row >= (HH * TT) ? 1 : 0;
  int rem = row - br * (HH * TT);
  int h = rem >> 9, t = rem & (TT - 1);
  const float* sr = scores + ((size_t)(br * HH + h) * TT + t) * TT;
  u64 run = sort64_desc(make_key(sr[lane], lane, t), lane);
#pragma unroll
  for (int e = 1; e < 8; e++) {
    u64 kb = sort64_desc(make_key(sr[e * 64 + lane], e * 64 + lane, t), lane);
    u64 rev = __shfl(kb, 63 - lane);
    run = run > rev ? run : rev;
    run = merge64_desc(run, lane);
  }
  unsigned myidx = ~(unsigned)run;
  unsigned outv = __shfl(myidx, min(lane, t));
  int* idxout = (br ? idx2 : idx1) + ((size_t)h * TT + t) * KKEEP;
  idxout[lane] = (int)outv;
}

// ---------------- register bitonic sort of 512 u64 keys across one wave (gate) -------
__device__ __forceinline__ void sort512(u64* key, int lane) {
#pragma unroll
  for (int k = 2; k <= 512; k <<= 1) {
#pragma unroll
    for (int j = k >> 1; j > 0; j >>= 1) {
      if (j < 64) {
        bool lower = (lane & j) == 0;
#pragma unroll
        for (int e = 0; e < 8; e++) {
          bool desc = ((((e << 6) | lane) & k) == 0);
          u64 part = __shfl_xor(key[e], j);
          bool wantmax = (desc == lower);
          key[e] = (wantmax ? (part > key[e]) : (part < key[e])) ? part : key[e];
        }
      } else {
        int m = j >> 6;
#pragma unroll
        for (int e = 0; e < 8; e++) {
          if ((e & m) == 0) {
            int e2 = e | m;
            bool desc = ((((e << 6) | lane) & k) == 0);
            u64 a = key[e], b = key[e2];
            u64 mx = a > b ? a : b;
            u64 mn = a > b ? b : a;
            key[e] = desc ? mx : mn;
            key[e2] = desc ? mn : mx;
          }
        }
      }
    }
  }
}

// ---------------- HOA core: MFMA (per (h,t) block, 4 waves), planes out ----------------
__global__ __launch_bounds__(256) void hoa_core_kernel(
    const float* __restrict__ qh,
    const float* __restrict__ K1, const float* __restrict__ K2,
    const float* __restrict__ V1, const float* __restrict__ V2,
    const int* __restrict__ idx1, const int* __restrict__ idx2,
    unsigned short* __restrict__ hcohi, unsigned short* __restrict__ hcolo) {
  int h = blockIdx.x, t = blockIdx.y, tid = threadIdx.x;
  int lane = tid & 63, w = tid >> 6;
  int lr = lane & 15;
  int ksub = (lane >> 4) * 8;
  const int hDD = h * DD;

  __shared__ unsigned short bufA[64 * 64];
  __shared__ unsigned short bufB[64 * 64];
  __shared__ float v1s[64 * 65];
  __shared__ float red[4 * 64];

  const int* i1 = idx1 + (h * TT + t) * KKEEP;
  const int* i2 = idx2 + (h * TT + t) * KKEEP;

  float qreg = qh[t * CC + hDD + lane];

#pragma unroll
  for (int r = 0; r < 16; r++) {
    int j = w * 16 + r;
    int r1 = i1[j], r2 = i2[j];
    float k1v = K1[(size_t)r1 * CC + hDD + lane];
    float k2v = K2[(size_t)r2 * CC + hDD + lane];
    float v1v = V1[(size_t)r1 * CC + hDD + lane];
    int off = swz(j, lane);
    bufA[off] = f32_to_bf16_rne(k1v * qreg);
    bufB[off] = f32_to_bf16_rne(k2v);
    v1s[j * 65 + lane] = v1v;
  }
  __syncthreads();

  f32x4 acc[4];
#pragma unroll
  for (int nt = 0; nt < 4; nt++) acc[nt] = (f32x4){0.f, 0.f, 0.f, 0.f};
  {
    bf16x8 af[2];
#pragma unroll
    for (int kb = 0; kb < 2; kb++)
      af[kb] = *(const bf16x8*)&bufA[swz(w * 16 + lr, kb * 32 + ksub)];
#pragma unroll
    for (int nt = 0; nt < 4; nt++)
#pragma unroll
      for (int kb = 0; kb < 2; kb++) {
        bf16x8 bf = *(const bf16x8*)&bufB[swz(nt * 16 + lr, kb * 32 + ksub)];
        acc[nt] = __builtin_amdgcn_mfma_f32_16x16x32_bf16(af[kb], bf, acc[nt], 0, 0, 0);
      }
  }
#pragma unroll
  for (int q = 0; q < 4; q++) {
    float m = -INFINITY;
#pragma unroll
    for (int nt = 0; nt < 4; nt++) {
      acc[nt][q] *= 0.125f;
      m = fmaxf(m, acc[nt][q]);
    }
#pragma unroll
    for (int off = 1; off < 16; off <<= 1) m = fmaxf(m, __shfl_xor(m, off));
    float s = 0.f;
#pragma unroll
    for (int nt = 0; nt < 4; nt++) {
      float e = expf(acc[nt][q] - m);
      acc[nt][q] = e;
      s += e;
    }
#pragma unroll
    for (int off = 1; off < 16; off <<= 1) s += __shfl_xor(s, off);
    float inv = 1.f / s;
#pragma unroll
    for (int nt = 0; nt < 4; nt++) acc[nt][q] *= inv;
  }
  __syncthreads();

#pragma unroll
  for (int nt = 0; nt < 4; nt++)
#pragma unroll
    for (int q = 0; q < 4; q++) {
      int row = w * 16 + (lane >> 4) * 4 + q;
      int col = nt * 16 + lr;
      bufA[swz(row, col)] = f32_to_bf16_rne(acc[nt][q]);
    }
#pragma unroll
  for (int r = 0; r < 16; r++) {
    int k = w * 16 + r;
    float v2v = V2[(size_t)i2[k] * CC + hDD + lane];
    bufB[swz(lane, k)] = f32_to_bf16_rne(v2v);
  }
  __syncthreads();

  f32x4 acc2[4];
#pragma unroll
  for (int nt = 0; nt < 4; nt++) acc2[nt] = (f32x4){0.f, 0.f, 0.f, 0.f};
  {
    bf16x8 af[2];
#pragma unroll
    for (int kb = 0; kb < 2; kb++)
      af[kb] = *(const bf16x8*)&bufA[swz(w * 16 + lr, kb * 32 + ksub)];
#pragma unroll
    for (int nt = 0; nt < 4; nt++)
#pragma unroll
      for (int kb = 0; kb < 2; kb++) {
        bf16x8 bf = *(const bf16x8*)&bufB[swz(nt * 16 + lr, kb * 32 + ksub)];
        acc2[nt] = __builtin_amdgcn_mfma_f32_16x16x32_bf16(af[kb], bf, acc2[nt], 0, 0, 0);
      }
  }
#pragma unroll
  for (int nt = 0; nt < 4; nt++) {
    float p = 0.f;
#pragma unroll
    for (int q = 0; q < 4; q++) {
      int row = w * 16 + (lane >> 4) * 4 + q;
      int col = lr + 16 * nt;
      p += acc2[nt][q] * v1s[row * 65 + col];
    }
    p += __shfl_xor(p, 16);
    p += __shfl_xor(p, 32);
    if (lane < 16) red[w * 64 + 16 * nt + lr] = p;
  }
  __syncthreads();
  if (tid < 64) {
    float o = red[tid] + red[64 + tid] + red[128 + tid] + red[192 + tid];
    unsigned short hb, lb;
    split2(o, hb, lb);
    hcohi[t * CC + hDD + tid] = hb;
    hcolo[t * CC + hDD + tid] = lb;
  }
}

// ---------------- gate ----------------
__global__ void gate_scores_kernel(const float* __restrict__ hoin,
                                   const float* __restrict__ gw, const float* __restrict__ gb,
                                   float* __restrict__ scores) {
  int t = blockIdx.x, tid = threadIdx.x;
  __shared__ float red[4];
  float part = 0.f;
  for (int c = tid; c < CC; c += 256) part += hoin[t * CC + c] * gw[c];
  float s = block_sum(part, red);
  if (tid == 0) scores[t] = s + gb[0];
}

__global__ void gate_mask_kernel(const float* __restrict__ scores, float* __restrict__ mask) {
  int lane = threadIdx.x;  // 64 threads, one wave
  u64 key[8];
#pragma unroll
  for (int e = 0; e < 8; e++) {
    int s = e * 64 + lane;
    unsigned uu = __float_as_uint(scores[s]);
    unsigned sv = (uu & 0x80000000u) ? ~uu : (uu | 0x80000000u);
    key[e] = ((u64)sv << 32) | (unsigned)(~s);
    mask[s] = 0.f;
  }
  __asm__ volatile("s_waitcnt vmcnt(0)" ::: "memory");
  sort512(key, lane);
#pragma unroll
  for (int e = 0; e < 2; e++) mask[(int)(~(unsigned)key[e])] = 1.f;
}

// ---------------- elementwise ----------------
__global__ void masked_add_kernel(const float* __restrict__ a, const float* __restrict__ b,
                                  const float* __restrict__ mask, float* __restrict__ o, int n) {
  int i = blockIdx.x * 256 + threadIdx.x;
  if (i < n) o[i] = a[i] + b[i] * mask[i / CC];
}

// ---------------- launcher ----------------
extern "C" void kernel_launch(void* const* d_in, const int* in_sizes, int n_in,
                              void* d_out, int out_size, void* d_ws, size_t ws_size,
                              hipStream_t stream) {
  const float* x      = (const float*)d_in[0];
  const float* ln1_w  = (const float*)d_in[1];
  const float* ln1_b  = (const float*)d_in[2];
  const float* qkv_w  = (const float*)d_in[3];
  const float* qkv_b  = (const float*)d_in[4];
  const float* atto_w = (const float*)d_in[5];
  const float* atto_b = (const float*)d_in[6];
  const float* lnh_w  = (const float*)d_in[7];
  const float* lnh_b  = (const float*)d_in[8];
  const float* hq_w   = (const float*)d_in[9];
  const float* hk1_w  = (const float*)d_in[10];
  const float* hk2_w  = (const float*)d_in[11];
  const float* hv1_w  = (const float*)d_in[12];
  const float* hv2_w  = (const float*)d_in[13];
  const float* ho_w   = (const float*)d_in[14];
  const float* gate_w = (const float*)d_in[15];
  const float* gate_b = (const float*)d_in[16];
  const float* ln2_w  = (const float*)d_in[17];
  const float* ln2_b  = (const float*)d_in[18];
  const float* fc_w   = (const float*)d_in[19];
  const float* fc_b   = (const float*)d_in[20];
  const float* pr_w   = (const float*)d_in[21];
  const float* pr_b   = (const float*)d_in[22];
  float* out = (float*)d_out;

  // workspace carve-up
  char* cur = (char*)d_ws;
  auto alloc = [&](size_t bytes) {
    char* p = cur;
    cur += (bytes + 255) & ~(size_t)255;
    return p;
  };
  float* qkv  = (float*)alloc((size_t)3 * NTCE * 4);
  float* x1   = (float*)alloc((size_t)NTCE * 4);
  float* hoin = (float*)alloc((size_t)NTCE * 4);
  float* qh   = (float*)alloc((size_t)5 * NTCE * 4);  // qh,K1,K2,V1,V2 contiguous
  float* K1   = qh + NTCE;
  float* K2   = K1 + NTCE;
  float* V1   = K2 + NTCE;
  float* V2   = V1 + NTCE;
  float* hout = (float*)alloc((size_t)NTCE * 4);
  float* x2   = (float*)alloc((size_t)NTCE * 4);
  float* scores = (float*)alloc(TT * 4);
  float* maskb  = (float*)alloc(TT * 4);
  int* idx1 = (int*)alloc((size_t)HH * TT * KKEEP * 4);
  int* idx2 = (int*)alloc((size_t)HH * TT * KKEEP * 4);
  float* hscores = (float*)alloc((size_t)2 * HH * TT * TT * 4);  // 25 MB
  // activation planes
  unsigned short* hHi    = (unsigned short*)alloc((size_t)NTCE * 2);
  unsigned short* hLo    = (unsigned short*)alloc((size_t)NTCE * 2);
  unsigned short* yHi    = (unsigned short*)alloc((size_t)NTCE * 2);
  unsigned short* yLo    = (unsigned short*)alloc((size_t)NTCE * 2);
  unsigned short* hoinHi = (unsigned short*)alloc((size_t)NTCE * 2);
  unsigned short* hoinLo = (unsigned short*)alloc((size_t)NTCE * 2);
  unsigned short* h2Hi   = (unsigned short*)alloc((size_t)NTCE * 2);
  unsigned short* h2Lo   = (unsigned short*)alloc((size_t)NTCE * 2);
  unsigned short* hcoHi  = (unsigned short*)alloc((size_t)NTCE * 2);
  unsigned short* hcoLo  = (unsigned short*)alloc((size_t)NTCE * 2);
  unsigned short* fcbHi  = (unsigned short*)alloc((size_t)4 * NTCE * 2);
  unsigned short* fcbLo  = (unsigned short*)alloc((size_t)4 * NTCE * 2);
  // weight planes (transposed [N][K])
  const size_t WSQ = (size_t)CC * CC;
  unsigned short* qkvT_h = (unsigned short*)alloc((size_t)CC * 3 * CC * 2);
  unsigned short* qkvT_l = (unsigned short*)alloc((size_t)CC * 3 * CC * 2);
  unsigned short* attoT_h = (unsigned short*)alloc(WSQ * 2);
  unsigned short* attoT_l = (unsigned short*)alloc(WSQ * 2);
  unsigned short* hoaT_h = (unsigned short*)alloc(5 * WSQ * 2);
  unsigned short* hoaT_l = (unsigned short*)alloc(5 * WSQ * 2);
  unsigned short* hoT_h = (unsigned short*)alloc(WSQ * 2);
  unsigned short* hoT_l = (unsigned short*)alloc(WSQ * 2);
  unsigned short* fcT_h = (unsigned short*)alloc((size_t)CC * 4 * CC * 2);
  unsigned short* fcT_l = (unsigned short*)alloc((size_t)CC * 4 * CC * 2);
  unsigned short* prT_h = (unsigned short*)alloc((size_t)CC * 4 * CC * 2);
  unsigned short* prT_l = (unsigned short*)alloc((size_t)CC * 4 * CC * 2);

  // weight split jobs
  WSplitArgs wa;
  int tcur = 0;
  auto addw = [&](int i, const float* s, unsigned short* hi, unsigned short* lo, int K, int N) {
    wa.src[i] = s; wa.hi[i] = hi; wa.lo[i] = lo;
    wa.K[i] = K; wa.N[i] = N; wa.tstart[i] = tcur;
    tcur += (N / 64) * (K / 64);
  };
  addw(0, qkv_w, qkvT_h, qkvT_l, CC, 3 * CC);
  addw(1, atto_w, attoT_h, attoT_l, CC, CC);
  addw(2, hq_w,  hoaT_h + 0 * WSQ, hoaT_l + 0 * WSQ, CC, CC);
  addw(3, hk1_w, hoaT_h + 1 * WSQ, hoaT_l + 1 * WSQ, CC, CC);
  addw(4, hk2_w, hoaT_h + 2 * WSQ, hoaT_l + 2 * WSQ, CC, CC);
  addw(5, hv1_w, hoaT_h + 3 * WSQ, hoaT_l + 3 * WSQ, CC, CC);
  addw(6, hv2_w, hoaT_h + 4 * WSQ, hoaT_l + 4 * WSQ, CC, CC);
  addw(7, ho_w, hoT_h, hoT_l, CC, CC);
  addw(8, fc_w, fcT_h, fcT_l, CC, 4 * CC);
  addw(9, pr_w, prT_h, prT_l, 4 * CC, CC);

  dim3 blk(256);
  int nElem = NTCE;
  int nBlocks = (nElem + 255) / 256;

  hipLaunchKernelGGL(wsplitT_kernel, dim3(tcur), blk, 0, stream, wa);
  // LN1 -> h planes
  hipLaunchKernelGGL(ln_bf_kernel, dim3(TT), blk, 0, stream, x, ln1_w, ln1_b,
                     (float*)nullptr, hHi, hLo);
  // QKV
  hipLaunchKernelGGL(gemm_bf, dim3(36, 8), blk, 0, stream, hHi, hLo, qkvT_h, qkvT_l,
                     qkv_b, qkv, (unsigned short*)nullptr, (unsigned short*)nullptr,
                     TT, 3 * CC, CC, 0, 0, (const float*)nullptr);
  // SDPA (flash MFMA) -> y planes
  hipLaunchKernelGGL(sdpa_mfma_kernel, dim3(HH, 8), blk, 0, stream, qkv, yHi, yLo);
  // atto + residual -> x1
  hipLaunchKernelGGL(gemm_bf, dim3(12, 8), blk, 0, stream, yHi, yLo, attoT_h, attoT_l,
                     atto_b, x1, (unsigned short*)nullptr, (unsigned short*)nullptr,
                     TT, CC, CC, 0, 0, x);
  // LNh -> hoin f32 + planes
  hipLaunchKernelGGL(ln_bf_kernel, dim3(TT), blk, 0, stream, x1, lnh_w, lnh_b,
                     hoin, hoinHi, hoinLo);
  // 5 HOA projections merged (N=3840, segmented out to qh..V2)
  hipLaunchKernelGGL(gemm_bf, dim3(60, 8), blk, 0, stream, hoinHi, hoinLo, hoaT_h, hoaT_l,
                     (const float*)nullptr, qh, (unsigned short*)nullptr, (unsigned short*)nullptr,
                     TT, 5 * CC, CC, 0, 1, (const float*)nullptr);
  // HOA scores (both branches) + wave top-64 selection
  hipLaunchKernelGGL(score_gemm_kernel, dim3(8, 8, 2 * HH), blk, 0, stream,
                     qh, K1, K2, hscores);
  hipLaunchKernelGGL(topk_select_kernel, dim3(2 * HH * TT / 4), blk, 0, stream,
                     hscores, idx1, idx2);
  // HOA core -> hco planes
  hipLaunchKernelGGL(hoa_core_kernel, dim3(HH, TT), blk, 0, stream,
                     qh, K1, K2, V1, V2, idx1, idx2, hcoHi, hcoLo);
  // ho -> hout
  hipLaunchKernelGGL(gemm_bf, dim3(12, 8), blk, 0, stream, hcoHi, hcoLo, hoT_h, hoT_l,
                     (const float*)nullptr, hout, (unsigned short*)nullptr, (unsigned short*)nullptr,
                     TT, CC, CC, 0, 0, (const float*)nullptr);
  // gate
  hipLaunchKernelGGL(gate_scores_kernel, dim3(TT), blk, 0, stream, hoin, gate_w, gate_b, scores);
  hipLaunchKernelGGL(gate_mask_kernel, dim3(1), dim3(64), 0, stream, scores, maskb);
  hipLaunchKernelGGL(masked_add_kernel, dim3(nBlocks), blk, 0, stream, x1, hout, maskb, x2, nElem);
  // LN2 -> h2 planes
  hipLaunchKernelGGL(ln_bf_kernel, dim3(TT), blk, 0, stream, x2, ln2_w, ln2_b,
                     (float*)nullptr, h2Hi, h2Lo);
  // fc (+gelu) -> fcb planes
  hipLaunchKernelGGL(gemm_bf, dim3(48, 8), blk, 0, stream, h2Hi, h2Lo, fcT_h, fcT_l,
                     fc_b, (float*)nullptr, fcbHi, fcbLo, TT, 4 * CC, CC, 1, 0,
                     (const float*)nullptr);
  // pr + residual -> out
  hipLaunchKernelGGL(gemm_bf, dim3(12, 8), blk, 0, stream, fcbHi, fcbLo, prT_h, prT_l,
                     pr_b, out, (unsigned short*)nullptr, (unsigned short*)nullptr,
                     TT, CC, 4 * CC, 0, 0, x2);
}

// Round 7
// 362.367 us; speedup vs baseline: 2.2987x; 1.0351x over previous
//
#include <hip/hip_runtime.h>
#include <hip/hip_bf16.h>
#include <math.h>

#define TT 512
#define CC 768
#define HH 12
#define DD 64
#define KKEEP 64
#define TOPG 128
#define NTCE (TT * CC)

typedef __attribute__((ext_vector_type(8))) short bf16x8;
typedef __attribute__((ext_vector_type(8))) unsigned short ushort8v;
typedef __attribute__((ext_vector_type(4))) float f32x4;
typedef unsigned long long u64;

// ---------------- helpers ----------------
__device__ __forceinline__ float block_sum(float v, float* red) {
#pragma unroll
  for (int off = 32; off; off >>= 1) v += __shfl_xor(v, off);
  __syncthreads();
  if ((threadIdx.x & 63) == 0) red[threadIdx.x >> 6] = v;
  __syncthreads();
  return red[0] + red[1] + red[2] + red[3];
}

__device__ __forceinline__ unsigned short f32_to_bf16_rne(float f) {
  unsigned u = __float_as_uint(f);
  unsigned r = (u + 0x7FFFu + ((u >> 16) & 1u)) >> 16;
  return (unsigned short)r;
}
__device__ __forceinline__ float bf16_to_f32(unsigned short h) {
  return __uint_as_float(((unsigned)h) << 16);
}
__device__ __forceinline__ void split2(float x, unsigned short& h, unsigned short& l) {
  h = f32_to_bf16_rne(x);
  l = f32_to_bf16_rne(x - bf16_to_f32(h));
}
__device__ __forceinline__ int swz(int row, int k) {
  return row * 64 + ((((k >> 3) ^ (row & 7))) << 3) + (k & 7);
}

// ---------------- weight split+transpose (all 10 weights, one dispatch) ----------------
struct WSplitArgs {
  const float* src[10];
  unsigned short* hi[10];
  unsigned short* lo[10];
  int K[10], N[10], tstart[10];
};

__global__ __launch_bounds__(256) void wsplitT_kernel(WSplitArgs a) {
  __shared__ float tile_[64][65];
  int t = blockIdx.x;
  int wsel = 0;
#pragma unroll
  for (int i = 1; i < 10; i++)
    if (t >= a.tstart[i]) wsel = i;
  int local = t - a.tstart[wsel];
  int K = a.K[wsel], N = a.N[wsel];
  int ntn = N >> 6;
  int bn = local % ntn, bk = local / ntn;
  int tid = threadIdx.x, r = tid >> 2, cq = tid & 3;
  const float* src = a.src[wsel] + (size_t)(bk * 64 + r) * N + bn * 64 + cq * 16;
#pragma unroll
  for (int f = 0; f < 4; f++) {
    float4 v = *(const float4*)(src + f * 4);
    tile_[r][cq * 16 + f * 4 + 0] = v.x;
    tile_[r][cq * 16 + f * 4 + 1] = v.y;
    tile_[r][cq * 16 + f * 4 + 2] = v.z;
    tile_[r][cq * 16 + f * 4 + 3] = v.w;
  }
  __syncthreads();
  size_t dst = (size_t)(bn * 64 + r) * K + bk * 64 + cq * 16;
  unsigned short hv[16], lv[16];
#pragma unroll
  for (int i = 0; i < 16; i++) split2(tile_[cq * 16 + i][r], hv[i], lv[i]);
  *(ushort8v*)&a.hi[wsel][dst] = *(const ushort8v*)&hv[0];
  *(ushort8v*)&a.hi[wsel][dst + 8] = *(const ushort8v*)&hv[8];
  *(ushort8v*)&a.lo[wsel][dst] = *(const ushort8v*)&lv[0];
  *(ushort8v*)&a.lo[wsel][dst + 8] = *(const ushort8v*)&lv[8];
}

// ---------------- layernorm (planes out; optional fused gate-score dot) ----------------
__global__ void ln_bf_kernel(const float* __restrict__ x, const float* __restrict__ w,
                             const float* __restrict__ b,
                             unsigned short* __restrict__ ohi, unsigned short* __restrict__ olo,
                             const float* __restrict__ gw, const float* __restrict__ gb,
                             float* __restrict__ gscore) {
  int t = blockIdx.x, tid = threadIdx.x;
  __shared__ float red[4];
  float ls = 0.f;
  for (int c = tid; c < CC; c += 256) ls += x[t * CC + c];
  float mean = block_sum(ls, red) * (1.f / CC);
  float lv = 0.f;
  for (int c = tid; c < CC; c += 256) { float d = x[t * CC + c] - mean; lv += d * d; }
  float var = block_sum(lv, red) * (1.f / CC);
  float rs = rsqrtf(var + 1e-5f);
  float gpart = 0.f;
  for (int c = tid; c < CC; c += 256) {
    float val = (x[t * CC + c] - mean) * rs * w[c] + b[c];
    if (gscore) gpart += val * gw[c];
    unsigned short hb, lb;
    split2(val, hb, lb);
    ohi[t * CC + c] = hb;
    olo[t * CC + c] = lb;
  }
  if (gscore) {
    float s = block_sum(gpart, red);
    if (tid == 0) gscore[t] = s + gb[0];
  }
}

// ---------------- split-bf16 MFMA GEMM from preconverted planes ----------------
__global__ __launch_bounds__(256) void gemm_bf(
    const unsigned short* __restrict__ Ah, const unsigned short* __restrict__ Al,
    const unsigned short* __restrict__ Bh, const unsigned short* __restrict__ Bl,
    const float* __restrict__ bias, float* __restrict__ Cf,
    unsigned short* __restrict__ Chi, unsigned short* __restrict__ Clo,
    int M, int N, int K, int act, int seg, const float* __restrict__ res,
    const float* __restrict__ rowmask) {
  __shared__ unsigned short AsH[64 * 64], AsL[64 * 64], BsH[64 * 64], BsL[64 * 64];
  int tid = threadIdx.x, lane = tid & 63, wave = tid >> 6;
  int wr = wave >> 1, wc = wave & 1, lr = lane & 15;
  int ksub = (lane >> 4) * 8;
  int n0 = blockIdx.x * 64, m0 = blockIdx.y * 64;
  int lrow = tid >> 2, lq = tid & 3;

  f32x4 acc[2][2];
#pragma unroll
  for (int i = 0; i < 2; i++)
#pragma unroll
    for (int j = 0; j < 2; j++) acc[i][j] = (f32x4){0.f, 0.f, 0.f, 0.f};

  for (int k0 = 0; k0 < K; k0 += 64) {
    size_t aoff = (size_t)(m0 + lrow) * K + k0 + lq * 16;
    size_t boff = (size_t)(n0 + lrow) * K + k0 + lq * 16;
    int d0 = lrow * 64 + (((lq * 2) ^ (lrow & 7)) << 3);
    int d1 = lrow * 64 + (((lq * 2 + 1) ^ (lrow & 7)) << 3);
    *(ushort8v*)&AsH[d0] = *(const ushort8v*)&Ah[aoff];
    *(ushort8v*)&AsH[d1] = *(const ushort8v*)&Ah[aoff + 8];
    *(ushort8v*)&AsL[d0] = *(const ushort8v*)&Al[aoff];
    *(ushort8v*)&AsL[d1] = *(const ushort8v*)&Al[aoff + 8];
    *(ushort8v*)&BsH[d0] = *(const ushort8v*)&Bh[boff];
    *(ushort8v*)&BsH[d1] = *(const ushort8v*)&Bh[boff + 8];
    *(ushort8v*)&BsL[d0] = *(const ushort8v*)&Bl[boff];
    *(ushort8v*)&BsL[d1] = *(const ushort8v*)&Bl[boff + 8];
    __syncthreads();
#pragma unroll
    for (int kb = 0; kb < 2; kb++) {
      int kloc = kb * 32 + ksub;
      bf16x8 ah[2], al[2], bh[2], bl[2];
#pragma unroll
      for (int i = 0; i < 2; i++) {
        int m = wr * 32 + i * 16 + lr;
        int off = swz(m, kloc);
        ah[i] = *(const bf16x8*)&AsH[off];
        al[i] = *(const bf16x8*)&AsL[off];
      }
#pragma unroll
      for (int j = 0; j < 2; j++) {
        int n = wc * 32 + j * 16 + lr;
        int off = swz(n, kloc);
        bh[j] = *(const bf16x8*)&BsH[off];
        bl[j] = *(const bf16x8*)&BsL[off];
      }
#pragma unroll
      for (int i = 0; i < 2; i++)
#pragma unroll
        for (int j = 0; j < 2; j++) {
          acc[i][j] = __builtin_amdgcn_mfma_f32_16x16x32_bf16(ah[i], bh[j], acc[i][j], 0, 0, 0);
          acc[i][j] = __builtin_amdgcn_mfma_f32_16x16x32_bf16(ah[i], bl[j], acc[i][j], 0, 0, 0);
          acc[i][j] = __builtin_amdgcn_mfma_f32_16x16x32_bf16(al[i], bh[j], acc[i][j], 0, 0, 0);
        }
    }
    __syncthreads();
  }
#pragma unroll
  for (int i = 0; i < 2; i++)
#pragma unroll
    for (int j = 0; j < 2; j++) {
      int col = n0 + wc * 32 + j * 16 + lr;
      float bv = bias ? bias[col] : 0.f;
#pragma unroll
      for (int q = 0; q < 4; q++) {
        int row = m0 + wr * 32 + i * 16 + (lane >> 4) * 4 + q;
        float v = acc[i][j][q] + bv;
        if (act == 1) v = 0.5f * v * (1.f + erff(v * 0.70710678118654752f));
        if (rowmask) v *= rowmask[row];
        if (Cf) {
          size_t off = seg ? (size_t)(col / CC) * NTCE + (size_t)row * CC + (col % CC)
                           : (size_t)row * N + col;
          if (res) v += res[off];
          Cf[off] = v;
        }
        if (Chi) {
          size_t o2 = (size_t)row * N + col;
          unsigned short hb, lb;
          split2(v, hb, lb);
          Chi[o2] = hb;
          Clo[o2] = lb;
        }
      }
    }
}

// ---------------- flash-style MFMA SDPA (per (h, 64-row t-tile), planes out) ----------
__global__ __launch_bounds__(256) void sdpa_mfma_kernel(
    const float* __restrict__ qkv,
    unsigned short* __restrict__ yhi, unsigned short* __restrict__ ylo) {
  int h = blockIdx.x, bt = blockIdx.y;
  int t0 = bt * 64;
  int tid = threadIdx.x, lane = tid & 63, w = tid >> 6;
  int lr = lane & 15, ksub = (lane >> 4) * 8;
  const int hDD = h * DD;

  __shared__ unsigned short qHi[64 * 64], qLo[64 * 64];
  __shared__ unsigned short kHi[64 * 64], kLo[64 * 64];
  __shared__ unsigned short bufP[64 * 64], bufV[64 * 64];

  int lrow = tid >> 2, lq = tid & 3;
  {
    const float* src = qkv + (size_t)(t0 + lrow) * (3 * CC) + hDD + lq * 16;
#pragma unroll
    for (int f = 0; f < 4; f++) {
      float4 v = *(const float4*)(src + f * 4);
      int kk = lq * 16 + f * 4;
      int off = swz(lrow, kk);
      unsigned short h0, h1, h2, h3, l0, l1, l2, l3;
      split2(v.x, h0, l0); split2(v.y, h1, l1); split2(v.z, h2, l2); split2(v.w, h3, l3);
      *(ushort4*)&qHi[off] = make_ushort4(h0, h1, h2, h3);
      *(ushort4*)&qLo[off] = make_ushort4(l0, l1, l2, l3);
    }
  }

  float m[4], l[4];
  f32x4 o[4];
#pragma unroll
  for (int q = 0; q < 4; q++) { m[q] = -INFINITY; l[q] = 0.f; }
#pragma unroll
  for (int nt = 0; nt < 4; nt++) o[nt] = (f32x4){0.f, 0.f, 0.f, 0.f};

  for (int st = 0; st <= bt; st++) {
    int s0 = st * 64;
    __syncthreads();
    {
      const float* src = qkv + (size_t)(s0 + lrow) * (3 * CC) + CC + hDD + lq * 16;
#pragma unroll
      for (int f = 0; f < 4; f++) {
        float4 v = *(const float4*)(src + f * 4);
        int kk = lq * 16 + f * 4;
        int off = swz(lrow, kk);
        unsigned short h0, h1, h2, h3, l0, l1, l2, l3;
        split2(v.x, h0, l0); split2(v.y, h1, l1); split2(v.z, h2, l2); split2(v.w, h3, l3);
        *(ushort4*)&kHi[off] = make_ushort4(h0, h1, h2, h3);
        *(ushort4*)&kLo[off] = make_ushort4(l0, l1, l2, l3);
      }
    }
#pragma unroll
    for (int r = 0; r < 16; r++) {
      int sl = w * 16 + r;
      float v = qkv[(size_t)(s0 + sl) * (3 * CC) + 2 * CC + hDD + lane];
      bufV[swz(lane, sl)] = f32_to_bf16_rne(v);
    }
    __syncthreads();
    f32x4 acc[4];
#pragma unroll
    for (int nt = 0; nt < 4; nt++) acc[nt] = (f32x4){0.f, 0.f, 0.f, 0.f};
    {
      bf16x8 ah[2], al[2];
#pragma unroll
      for (int kb = 0; kb < 2; kb++) {
        int off = swz(w * 16 + lr, kb * 32 + ksub);
        ah[kb] = *(const bf16x8*)&qHi[off];
        al[kb] = *(const bf16x8*)&qLo[off];
      }
#pragma unroll
      for (int nt = 0; nt < 4; nt++)
#pragma unroll
        for (int kb = 0; kb < 2; kb++) {
          int off = swz(nt * 16 + lr, kb * 32 + ksub);
          bf16x8 bh = *(const bf16x8*)&kHi[off];
          bf16x8 bl = *(const bf16x8*)&kLo[off];
          acc[nt] = __builtin_amdgcn_mfma_f32_16x16x32_bf16(ah[kb], bh, acc[nt], 0, 0, 0);
          acc[nt] = __builtin_amdgcn_mfma_f32_16x16x32_bf16(ah[kb], bl, acc[nt], 0, 0, 0);
          acc[nt] = __builtin_amdgcn_mfma_f32_16x16x32_bf16(al[kb], bh, acc[nt], 0, 0, 0);
        }
    }
#pragma unroll
    for (int q = 0; q < 4; q++) {
      int trow = t0 + w * 16 + (lane >> 4) * 4 + q;
      float tm = -INFINITY;
#pragma unroll
      for (int nt = 0; nt < 4; nt++) {
        float v = acc[nt][q] * 0.125f;
        if (s0 + nt * 16 + lr > trow) v = -INFINITY;
        acc[nt][q] = v;
        tm = fmaxf(tm, v);
      }
#pragma unroll
      for (int off = 1; off < 16; off <<= 1) tm = fmaxf(tm, __shfl_xor(tm, off));
      float mn = fmaxf(m[q], tm);
      float scale = expf(m[q] - mn);
      float ps = 0.f;
#pragma unroll
      for (int nt = 0; nt < 4; nt++) {
        float e = expf(acc[nt][q] - mn);
        acc[nt][q] = e;
        ps += e;
      }
#pragma unroll
      for (int off = 1; off < 16; off <<= 1) ps += __shfl_xor(ps, off);
      l[q] = l[q] * scale + ps;
      m[q] = mn;
#pragma unroll
      for (int nt = 0; nt < 4; nt++) o[nt][q] *= scale;
    }
#pragma unroll
    for (int nt = 0; nt < 4; nt++)
#pragma unroll
      for (int q = 0; q < 4; q++) {
        int row = w * 16 + (lane >> 4) * 4 + q;
        int col = nt * 16 + lr;
        bufP[swz(row, col)] = f32_to_bf16_rne(acc[nt][q]);
      }
    __syncthreads();
    {
      bf16x8 pf[2];
#pragma unroll
      for (int kb = 0; kb < 2; kb++)
        pf[kb] = *(const bf16x8*)&bufP[swz(w * 16 + lr, kb * 32 + ksub)];
#pragma unroll
      for (int nt = 0; nt < 4; nt++)
#pragma unroll
        for (int kb = 0; kb < 2; kb++) {
          bf16x8 bv = *(const bf16x8*)&bufV[swz(nt * 16 + lr, kb * 32 + ksub)];
          o[nt] = __builtin_amdgcn_mfma_f32_16x16x32_bf16(pf[kb], bv, o[nt], 0, 0, 0);
        }
    }
  }
#pragma unroll
  for (int nt = 0; nt < 4; nt++)
#pragma unroll
    for (int q = 0; q < 4; q++) {
      int trow = t0 + w * 16 + (lane >> 4) * 4 + q;
      int d = nt * 16 + lr;
      float v = o[nt][q] / l[q];
      unsigned short hb, lb;
      split2(v, hb, lb);
      yhi[(size_t)trow * CC + hDD + d] = hb;
      ylo[(size_t)trow * CC + hDD + d] = lb;
    }
}

// ---------------- HOA score GEMM: scores[bh][t][s] = q_h[t,:] . K_h[s,:] ----------------
__global__ __launch_bounds__(256) void score_gemm_kernel(
    const float* __restrict__ qh, const float* __restrict__ K1, const float* __restrict__ K2,
    float* __restrict__ scores) {
  if (blockIdx.x > blockIdx.y) return;
  int bh = blockIdx.z;
  int br = bh >= HH ? 1 : 0;
  int h = bh - br * HH;
  const float* Kb = br ? K2 : K1;
  int s0 = blockIdx.x * 64, t0 = blockIdx.y * 64;
  int hDD = h * DD;
  __shared__ unsigned short AsH[64 * 64], AsL[64 * 64], BsH[64 * 64], BsL[64 * 64];
  int tid = threadIdx.x, lane = tid & 63, wave = tid >> 6;
  int wr = wave >> 1, wc = wave & 1, lr = lane & 15;
  int ksub = (lane >> 4) * 8;
  int lrow = tid >> 2, lq = tid & 3;
  {
    const float* srcA = qh + (size_t)(t0 + lrow) * CC + hDD + lq * 16;
    const float* srcB = Kb + (size_t)(s0 + lrow) * CC + hDD + lq * 16;
#pragma unroll
    for (int f = 0; f < 4; f++) {
      float4 va = *(const float4*)(srcA + f * 4);
      float4 vb = *(const float4*)(srcB + f * 4);
      int kk = lq * 16 + f * 4;
      int off = swz(lrow, kk);
      unsigned short h0, h1, h2, h3, l0, l1, l2, l3;
      split2(va.x, h0, l0); split2(va.y, h1, l1); split2(va.z, h2, l2); split2(va.w, h3, l3);
      *(ushort4*)&AsH[off] = make_ushort4(h0, h1, h2, h3);
      *(ushort4*)&AsL[off] = make_ushort4(l0, l1, l2, l3);
      split2(vb.x, h0, l0); split2(vb.y, h1, l1); split2(vb.z, h2, l2); split2(vb.w, h3, l3);
      *(ushort4*)&BsH[off] = make_ushort4(h0, h1, h2, h3);
      *(ushort4*)&BsL[off] = make_ushort4(l0, l1, l2, l3);
    }
  }
  __syncthreads();
  f32x4 acc[2][2];
#pragma unroll
  for (int i = 0; i < 2; i++)
#pragma unroll
    for (int j = 0; j < 2; j++) acc[i][j] = (f32x4){0.f, 0.f, 0.f, 0.f};
#pragma unroll
  for (int kb = 0; kb < 2; kb++) {
    int kloc = kb * 32 + ksub;
    bf16x8 ah[2], al[2], bh_[2], bl[2];
#pragma unroll
    for (int i = 0; i < 2; i++) {
      int m = wr * 32 + i * 16 + lr;
      int off = swz(m, kloc);
      ah[i] = *(const bf16x8*)&AsH[off];
      al[i] = *(const bf16x8*)&AsL[off];
    }
#pragma unroll
    for (int j = 0; j < 2; j++) {
      int n = wc * 32 + j * 16 + lr;
      int off = swz(n, kloc);
      bh_[j] = *(const bf16x8*)&BsH[off];
      bl[j] = *(const bf16x8*)&BsL[off];
    }
#pragma unroll
    for (int i = 0; i < 2; i++)
#pragma unroll
      for (int j = 0; j < 2; j++) {
        acc[i][j] = __builtin_amdgcn_mfma_f32_16x16x32_bf16(ah[i], bh_[j], acc[i][j], 0, 0, 0);
        acc[i][j] = __builtin_amdgcn_mfma_f32_16x16x32_bf16(ah[i], bl[j], acc[i][j], 0, 0, 0);
        acc[i][j] = __builtin_amdgcn_mfma_f32_16x16x32_bf16(al[i], bh_[j], acc[i][j], 0, 0, 0);
      }
  }
#pragma unroll
  for (int i = 0; i < 2; i++)
#pragma unroll
    for (int j = 0; j < 2; j++)
#pragma unroll
      for (int q = 0; q < 4; q++) {
        int tt = t0 + wr * 32 + i * 16 + (lane >> 4) * 4 + q;
        int ss = s0 + wc * 32 + j * 16 + lr;
        scores[((size_t)bh * TT + tt) * TT + ss] = acc[i][j][q];
      }
}

// ---------------- wave top-64 selection: chunk-skip + tree merge ----------------
__device__ __forceinline__ u64 cas_u64(u64 x, int j, bool dirmax, int lane) {
  u64 y = __shfl_xor(x, j);
  bool lower = (lane & j) == 0;
  bool keepmax = (dirmax == lower);
  return (keepmax ? (y > x) : (y < x)) ? y : x;
}
__device__ __forceinline__ u64 sort64_desc(u64 x, int lane) {
#pragma unroll
  for (int k = 2; k <= 64; k <<= 1) {
    bool dirmax = ((lane & k) == 0);
#pragma unroll
    for (int j = k >> 1; j; j >>= 1) x = cas_u64(x, j, dirmax, lane);
  }
  return x;
}
__device__ __forceinline__ u64 merge64_desc(u64 x, int lane) {
#pragma unroll
  for (int j = 32; j; j >>= 1) x = cas_u64(x, j, true, lane);
  return x;
}
// top-64 of two descending-sorted 64-lists
__device__ __forceinline__ u64 merge2_desc(u64 a, u64 b, int lane) {
  u64 rev = __shfl(b, 63 - lane);
  u64 run = a > rev ? a : rev;
  return merge64_desc(run, lane);
}
__device__ __forceinline__ u64 make_key(float v, int s, int t) {
  unsigned sv = 0u;
  if (s <= t) {
    unsigned u = __float_as_uint(v);
    sv = (u & 0x80000000u) ? ~u : (u | 0x80000000u);
  }
  return ((u64)sv << 32) | (unsigned)(~s);
}

__global__ __launch_bounds__(256) void topk_select_kernel(
    const float* __restrict__ scores, int* __restrict__ idx1, int* __restrict__ idx2) {
  int tid = threadIdx.x, lane = tid & 63, w = tid >> 6;
  int row = blockIdx.x * 4 + w;
  int br = row >= (HH * TT) ? 1 : 0;
  int rem = row - br * (HH * TT);
  int h = rem >> 9, t = rem & (TT - 1);
  const float* sr = scores + ((size_t)(br * HH + h) * TT + t) * TT;
  int nc = (t >> 6) + 1;
  u64 c[8];
#pragma unroll
  for (int e = 0; e < 8; e++) {
    if (e < nc)
      c[e] = sort64_desc(make_key(sr[e * 64 + lane], e * 64 + lane, t), lane);
    else
      c[e] = (u64)(unsigned)(~(e * 64 + lane));  // all-masked chunk: pre-sorted
  }
  // tree merge with wave-uniform skip of empty right halves
  u64 l10 = (t >= 64)  ? merge2_desc(c[0], c[1], lane) : c[0];
  u64 l11 = (t >= 192) ? merge2_desc(c[2], c[3], lane) : c[2];
  u64 l12 = (t >= 320) ? merge2_desc(c[4], c[5], lane) : c[4];
  u64 l13 = (t >= 448) ? merge2_desc(c[6], c[7], lane) : c[6];
  u64 l20 = (t >= 128) ? merge2_desc(l10, l11, lane) : l10;
  u64 l21 = (t >= 384) ? merge2_desc(l12, l13, lane) : l12;
  u64 res = (t >= 256) ? merge2_desc(l20, l21, lane) : l20;
  unsigned myidx = ~(unsigned)res;
  unsigned outv = __shfl(myidx, min(lane, t));  // clip/pad rule
  int* idxout = (br ? idx2 : idx1) + ((size_t)h * TT + t) * KKEEP;
  idxout[lane] = (int)outv;
}

// ---------------- register bitonic sort of 512 u64 keys across one wave (gate) -------
__device__ __forceinline__ void sort512(u64* key, int lane) {
#pragma unroll
  for (int k = 2; k <= 512; k <<= 1) {
#pragma unroll
    for (int j = k >> 1; j > 0; j >>= 1) {
      if (j < 64) {
        bool lower = (lane & j) == 0;
#pragma unroll
        for (int e = 0; e < 8; e++) {
          bool desc = ((((e << 6) | lane) & k) == 0);
          u64 part = __shfl_xor(key[e], j);
          bool wantmax = (desc == lower);
          key[e] = (wantmax ? (part > key[e]) : (part < key[e])) ? part : key[e];
        }
      } else {
        int m = j >> 6;
#pragma unroll
        for (int e = 0; e < 8; e++) {
          if ((e & m) == 0) {
            int e2 = e | m;
            bool desc = ((((e << 6) | lane) & k) == 0);
            u64 a = key[e], b = key[e2];
            u64 mx = a > b ? a : b;
            u64 mn = a > b ? b : a;
            key[e] = desc ? mx : mn;
            key[e2] = desc ? mn : mx;
          }
        }
      }
    }
  }
}

// ---------------- HOA core: MFMA (per (h,t) block, 4 waves), planes out ----------------
__global__ __launch_bounds__(256) void hoa_core_kernel(
    const float* __restrict__ qh,
    const float* __restrict__ K1, const float* __restrict__ K2,
    const float* __restrict__ V1, const float* __restrict__ V2,
    const int* __restrict__ idx1, const int* __restrict__ idx2,
    unsigned short* __restrict__ hcohi, unsigned short* __restrict__ hcolo) {
  int h = blockIdx.x, t = blockIdx.y, tid = threadIdx.x;
  int lane = tid & 63, w = tid >> 6;
  int lr = lane & 15;
  int ksub = (lane >> 4) * 8;
  const int hDD = h * DD;

  __shared__ unsigned short bufA[64 * 64];
  __shared__ unsigned short bufB[64 * 64];
  __shared__ float v1s[64 * 65];
  __shared__ float red[4 * 64];

  const int* i1 = idx1 + (h * TT + t) * KKEEP;
  const int* i2 = idx2 + (h * TT + t) * KKEEP;

  float qreg = qh[t * CC + hDD + lane];

#pragma unroll
  for (int r = 0; r < 16; r++) {
    int j = w * 16 + r;
    int r1 = i1[j], r2 = i2[j];
    float k1v = K1[(size_t)r1 * CC + hDD + lane];
    float k2v = K2[(size_t)r2 * CC + hDD + lane];
    float v1v = V1[(size_t)r1 * CC + hDD + lane];
    int off = swz(j, lane);
    bufA[off] = f32_to_bf16_rne(k1v * qreg);
    bufB[off] = f32_to_bf16_rne(k2v);
    v1s[j * 65 + lane] = v1v;
  }
  __syncthreads();

  f32x4 acc[4];
#pragma unroll
  for (int nt = 0; nt < 4; nt++) acc[nt] = (f32x4){0.f, 0.f, 0.f, 0.f};
  {
    bf16x8 af[2];
#pragma unroll
    for (int kb = 0; kb < 2; kb++)
      af[kb] = *(const bf16x8*)&bufA[swz(w * 16 + lr, kb * 32 + ksub)];
#pragma unroll
    for (int nt = 0; nt < 4; nt++)
#pragma unroll
      for (int kb = 0; kb < 2; kb++) {
        bf16x8 bf = *(const bf16x8*)&bufB[swz(nt * 16 + lr, kb * 32 + ksub)];
        acc[nt] = __builtin_amdgcn_mfma_f32_16x16x32_bf16(af[kb], bf, acc[nt], 0, 0, 0);
      }
  }
#pragma unroll
  for (int q = 0; q < 4; q++) {
    float m = -INFINITY;
#pragma unroll
    for (int nt = 0; nt < 4; nt++) {
      acc[nt][q] *= 0.125f;
      m = fmaxf(m, acc[nt][q]);
    }
#pragma unroll
    for (int off = 1; off < 16; off <<= 1) m = fmaxf(m, __shfl_xor(m, off));
    float s = 0.f;
#pragma unroll
    for (int nt = 0; nt < 4; nt++) {
      float e = expf(acc[nt][q] - m);
      acc[nt][q] = e;
      s += e;
    }
#pragma unroll
    for (int off = 1; off < 16; off <<= 1) s += __shfl_xor(s, off);
    float inv = 1.f / s;
#pragma unroll
    for (int nt = 0; nt < 4; nt++) acc[nt][q] *= inv;
  }
  __syncthreads();

#pragma unroll
  for (int nt = 0; nt < 4; nt++)
#pragma unroll
    for (int q = 0; q < 4; q++) {
      int row = w * 16 + (lane >> 4) * 4 + q;
      int col = nt * 16 + lr;
      bufA[swz(row, col)] = f32_to_bf16_rne(acc[nt][q]);
    }
#pragma unroll
  for (int r = 0; r < 16; r++) {
    int k = w * 16 + r;
    float v2v = V2[(size_t)i2[k] * CC + hDD + lane];
    bufB[swz(lane, k)] = f32_to_bf16_rne(v2v);
  }
  __syncthreads();

  f32x4 acc2[4];
#pragma unroll
  for (int nt = 0; nt < 4; nt++) acc2[nt] = (f32x4){0.f, 0.f, 0.f, 0.f};
  {
    bf16x8 af[2];
#pragma unroll
    for (int kb = 0; kb < 2; kb++)
      af[kb] = *(const bf16x8*)&bufA[swz(w * 16 + lr, kb * 32 + ksub)];
#pragma unroll
    for (int nt = 0; nt < 4; nt++)
#pragma unroll
      for (int kb = 0; kb < 2; kb++) {
        bf16x8 bf = *(const bf16x8*)&bufB[swz(nt * 16 + lr, kb * 32 + ksub)];
        acc2[nt] = __builtin_amdgcn_mfma_f32_16x16x32_bf16(af[kb], bf, acc2[nt], 0, 0, 0);
      }
  }
#pragma unroll
  for (int nt = 0; nt < 4; nt++) {
    float p = 0.f;
#pragma unroll
    for (int q = 0; q < 4; q++) {
      int row = w * 16 + (lane >> 4) * 4 + q;
      int col = lr + 16 * nt;
      p += acc2[nt][q] * v1s[row * 65 + col];
    }
    p += __shfl_xor(p, 16);
    p += __shfl_xor(p, 32);
    if (lane < 16) red[w * 64 + 16 * nt + lr] = p;
  }
  __syncthreads();
  if (tid < 64) {
    float o = red[tid] + red[64 + tid] + red[128 + tid] + red[192 + tid];
    unsigned short hb, lb;
    split2(o, hb, lb);
    hcohi[t * CC + hDD + tid] = hb;
    hcolo[t * CC + hDD + tid] = lb;
  }
}

// ---------------- gate mask ----------------
__global__ void gate_mask_kernel(const float* __restrict__ scores, float* __restrict__ mask) {
  int lane = threadIdx.x;  // 64 threads, one wave
  u64 key[8];
#pragma unroll
  for (int e = 0; e < 8; e++) {
    int s = e * 64 + lane;
    unsigned uu = __float_as_uint(scores[s]);
    unsigned sv = (uu & 0x80000000u) ? ~uu : (uu | 0x80000000u);
    key[e] = ((u64)sv << 32) | (unsigned)(~s);
    mask[s] = 0.f;
  }
  __asm__ volatile("s_waitcnt vmcnt(0)" ::: "memory");
  sort512(key, lane);
#pragma unroll
  for (int e = 0; e < 2; e++) mask[(int)(~(unsigned)key[e])] = 1.f;
}

// ---------------- launcher ----------------
extern "C" void kernel_launch(void* const* d_in, const int* in_sizes, int n_in,
                              void* d_out, int out_size, void* d_ws, size_t ws_size,
                              hipStream_t stream) {
  const float* x      = (const float*)d_in[0];
  const float* ln1_w  = (const float*)d_in[1];
  const float* ln1_b  = (const float*)d_in[2];
  const float* qkv_w  = (const float*)d_in[3];
  const float* qkv_b  = (const float*)d_in[4];
  const float* atto_w = (const float*)d_in[5];
  const float* atto_b = (const float*)d_in[6];
  const float* lnh_w  = (const float*)d_in[7];
  const float* lnh_b  = (const float*)d_in[8];
  const float* hq_w   = (const float*)d_in[9];
  const float* hk1_w  = (const float*)d_in[10];
  const float* hk2_w  = (const float*)d_in[11];
  const float* hv1_w  = (const float*)d_in[12];
  const float* hv2_w  = (const float*)d_in[13];
  const float* ho_w   = (const float*)d_in[14];
  const float* gate_w = (const float*)d_in[15];
  const float* gate_b = (const float*)d_in[16];
  const float* ln2_w  = (const float*)d_in[17];
  const float* ln2_b  = (const float*)d_in[18];
  const float* fc_w   = (const float*)d_in[19];
  const float* fc_b   = (const float*)d_in[20];
  const float* pr_w   = (const float*)d_in[21];
  const float* pr_b   = (const float*)d_in[22];
  float* out = (float*)d_out;

  // workspace carve-up
  char* cur = (char*)d_ws;
  auto alloc = [&](size_t bytes) {
    char* p = cur;
    cur += (bytes + 255) & ~(size_t)255;
    return p;
  };
  float* qkv  = (float*)alloc((size_t)3 * NTCE * 4);
  float* x1   = (float*)alloc((size_t)NTCE * 4);
  float* qh   = (float*)alloc((size_t)5 * NTCE * 4);  // qh,K1,K2,V1,V2 contiguous
  float* K1   = qh + NTCE;
  float* K2   = K1 + NTCE;
  float* V1   = K2 + NTCE;
  float* V2   = V1 + NTCE;
  float* x2   = (float*)alloc((size_t)NTCE * 4);
  float* scores = (float*)alloc(TT * 4);
  float* maskb  = (float*)alloc(TT * 4);
  int* idx1 = (int*)alloc((size_t)HH * TT * KKEEP * 4);
  int* idx2 = (int*)alloc((size_t)HH * TT * KKEEP * 4);
  float* hscores = (float*)alloc((size_t)2 * HH * TT * TT * 4);  // 25 MB
  // activation planes
  unsigned short* hHi    = (unsigned short*)alloc((size_t)NTCE * 2);
  unsigned short* hLo    = (unsigned short*)alloc((size_t)NTCE * 2);
  unsigned short* yHi    = (unsigned short*)alloc((size_t)NTCE * 2);
  unsigned short* yLo    = (unsigned short*)alloc((size_t)NTCE * 2);
  unsigned short* hoinHi = (unsigned short*)alloc((size_t)NTCE * 2);
  unsigned short* hoinLo = (unsigned short*)alloc((size_t)NTCE * 2);
  unsigned short* h2Hi   = (unsigned short*)alloc((size_t)NTCE * 2);
  unsigned short* h2Lo   = (unsigned short*)alloc((size_t)NTCE * 2);
  unsigned short* hcoHi  = (unsigned short*)alloc((size_t)NTCE * 2);
  unsigned short* hcoLo  = (unsigned short*)alloc((size_t)NTCE * 2);
  unsigned short* fcbHi  = (unsigned short*)alloc((size_t)4 * NTCE * 2);
  unsigned short* fcbLo  = (unsigned short*)alloc((size_t)4 * NTCE * 2);
  // weight planes (transposed [N][K])
  const size_t WSQ = (size_t)CC * CC;
  unsigned short* qkvT_h = (unsigned short*)alloc((size_t)CC * 3 * CC * 2);
  unsigned short* qkvT_l = (unsigned short*)alloc((size_t)CC * 3 * CC * 2);
  unsigned short* attoT_h = (unsigned short*)alloc(WSQ * 2);
  unsigned short* attoT_l = (unsigned short*)alloc(WSQ * 2);
  unsigned short* hoaT_h = (unsigned short*)alloc(5 * WSQ * 2);
  unsigned short* hoaT_l = (unsigned short*)alloc(5 * WSQ * 2);
  unsigned short* hoT_h = (unsigned short*)alloc(WSQ * 2);
  unsigned short* hoT_l = (unsigned short*)alloc(WSQ * 2);
  unsigned short* fcT_h = (unsigned short*)alloc((size_t)CC * 4 * CC * 2);
  unsigned short* fcT_l = (unsigned short*)alloc((size_t)CC * 4 * CC * 2);
  unsigned short* prT_h = (unsigned short*)alloc((size_t)CC * 4 * CC * 2);
  unsigned short* prT_l = (unsigned short*)alloc((size_t)CC * 4 * CC * 2);

  // weight split jobs
  WSplitArgs wa;
  int tcur = 0;
  auto addw = [&](int i, const float* s, unsigned short* hi, unsigned short* lo, int K, int N) {
    wa.src[i] = s; wa.hi[i] = hi; wa.lo[i] = lo;
    wa.K[i] = K; wa.N[i] = N; wa.tstart[i] = tcur;
    tcur += (N / 64) * (K / 64);
  };
  addw(0, qkv_w, qkvT_h, qkvT_l, CC, 3 * CC);
  addw(1, atto_w, attoT_h, attoT_l, CC, CC);
  addw(2, hq_w,  hoaT_h + 0 * WSQ, hoaT_l + 0 * WSQ, CC, CC);
  addw(3, hk1_w, hoaT_h + 1 * WSQ, hoaT_l + 1 * WSQ, CC, CC);
  addw(4, hk2_w, hoaT_h + 2 * WSQ, hoaT_l + 2 * WSQ, CC, CC);
  addw(5, hv1_w, hoaT_h + 3 * WSQ, hoaT_l + 3 * WSQ, CC, CC);
  addw(6, hv2_w, hoaT_h + 4 * WSQ, hoaT_l + 4 * WSQ, CC, CC);
  addw(7, ho_w, hoT_h, hoT_l, CC, CC);
  addw(8, fc_w, fcT_h, fcT_l, CC, 4 * CC);
  addw(9, pr_w, prT_h, prT_l, 4 * CC, CC);

  dim3 blk(256);

  hipLaunchKernelGGL(wsplitT_kernel, dim3(tcur), blk, 0, stream, wa);
  // LN1 -> h planes
  hipLaunchKernelGGL(ln_bf_kernel, dim3(TT), blk, 0, stream, x, ln1_w, ln1_b,
                     hHi, hLo, (const float*)nullptr, (const float*)nullptr, (float*)nullptr);
  // QKV
  hipLaunchKernelGGL(gemm_bf, dim3(36, 8), blk, 0, stream, hHi, hLo, qkvT_h, qkvT_l,
                     qkv_b, qkv, (unsigned short*)nullptr, (unsigned short*)nullptr,
                     TT, 3 * CC, CC, 0, 0, (const float*)nullptr, (const float*)nullptr);
  // SDPA (flash MFMA) -> y planes
  hipLaunchKernelGGL(sdpa_mfma_kernel, dim3(HH, 8), blk, 0, stream, qkv, yHi, yLo);
  // atto + residual -> x1
  hipLaunchKernelGGL(gemm_bf, dim3(12, 8), blk, 0, stream, yHi, yLo, attoT_h, attoT_l,
                     atto_b, x1, (unsigned short*)nullptr, (unsigned short*)nullptr,
                     TT, CC, CC, 0, 0, x, (const float*)nullptr);
  // LNh -> hoin planes + fused gate scores
  hipLaunchKernelGGL(ln_bf_kernel, dim3(TT), blk, 0, stream, x1, lnh_w, lnh_b,
                     hoinHi, hoinLo, gate_w, gate_b, scores);
  // gate mask
  hipLaunchKernelGGL(gate_mask_kernel, dim3(1), dim3(64), 0, stream, scores, maskb);
  // 5 HOA projections merged (N=3840, segmented out to qh..V2)
  hipLaunchKernelGGL(gemm_bf, dim3(60, 8), blk, 0, stream, hoinHi, hoinLo, hoaT_h, hoaT_l,
                     (const float*)nullptr, qh, (unsigned short*)nullptr, (unsigned short*)nullptr,
                     TT, 5 * CC, CC, 0, 1, (const float*)nullptr, (const float*)nullptr);
  // HOA scores (both branches) + wave top-64 selection
  hipLaunchKernelGGL(score_gemm_kernel, dim3(8, 8, 2 * HH), blk, 0, stream,
                     qh, K1, K2, hscores);
  hipLaunchKernelGGL(topk_select_kernel, dim3(2 * HH * TT / 4), blk, 0, stream,
                     hscores, idx1, idx2);
  // HOA core -> hco planes
  hipLaunchKernelGGL(hoa_core_kernel, dim3(HH, TT), blk, 0, stream,
                     qh, K1, K2, V1, V2, idx1, idx2, hcoHi, hcoLo);
  // ho GEMM with gate-mask + residual -> x2
  hipLaunchKernelGGL(gemm_bf, dim3(12, 8), blk, 0, stream, hcoHi, hcoLo, hoT_h, hoT_l,
                     (const float*)nullptr, x2, (unsigned short*)nullptr, (unsigned short*)nullptr,
                     TT, CC, CC, 0, 0, x1, maskb);
  // LN2 -> h2 planes
  hipLaunchKernelGGL(ln_bf_kernel, dim3(TT), blk, 0, stream, x2, ln2_w, ln2_b,
                     h2Hi, h2Lo, (const float*)nullptr, (const float*)nullptr, (float*)nullptr);
  // fc (+gelu) -> fcb planes
  hipLaunchKernelGGL(gemm_bf, dim3(48, 8), blk, 0, stream, h2Hi, h2Lo, fcT_h, fcT_l,
                     fc_b, (float*)nullptr, fcbHi, fcbLo, TT, 4 * CC, CC, 1, 0,
                     (const float*)nullptr, (const float*)nullptr);
  // pr + residual -> out
  hipLaunchKernelGGL(gemm_bf, dim3(12, 8), blk, 0, stream, fcbHi, fcbLo, prT_h, prT_l,
                     pr_b, out, (unsigned short*)nullptr, (unsigned short*)nullptr,
                     TT, CC, 4 * CC, 0, 0, x2, (const float*)nullptr);
}